// Round 8
// baseline (1188.562 us; speedup 1.0000x reference)
//
#include <hip/hip_runtime.h>
#include <math.h>

#define B_ 8
#define D_ 1024
#define N_ 4096
#define K_ 64
#define H_ 512

typedef short sx8 __attribute__((ext_vector_type(8)));
typedef float fx4 __attribute__((ext_vector_type(4)));

// ---------------- helpers ----------------
__device__ __forceinline__ float block_reduce_sum256(float v, float* sm) {
  int tid = threadIdx.x;
  sm[tid] = v;
  __syncthreads();
  for (int s = 128; s > 0; s >>= 1) {
    if (tid < s) sm[tid] += sm[tid + s];
    __syncthreads();
  }
  float r = sm[0];
  __syncthreads();
  return r;
}

__device__ __forceinline__ ushort f2bf(float f) {
  unsigned u = __float_as_uint(f);
  unsigned r = (u + 0x7fffu + ((u >> 16) & 1u)) >> 16;
  return (ushort)r;
}
__device__ __forceinline__ float bf2f(ushort h) {
  return __uint_as_float(((unsigned)h) << 16);
}

// ---------------- fused weight split (w1,w2,w3 in one launch) ----------------
__global__ __launch_bounds__(256)
void split_w3(const float* __restrict__ W1, const float* __restrict__ W2,
              const float* __restrict__ W3, ushort* __restrict__ Wh1,
              ushort* __restrict__ Wl1, ushort* __restrict__ Wh2,
              ushort* __restrict__ Wl2, ushort* __restrict__ Wh3,
              ushort* __restrict__ Wl3) {
  int i = blockIdx.x * 256 + threadIdx.x;
  const float* W;
  ushort *Wh, *Wl;
  int o;
  if (i < 524288) { W = W1; Wh = Wh1; Wl = Wl1; o = i; }
  else if (i < 786432) { W = W2; Wh = Wh2; Wl = Wl2; o = i - 524288; }
  else { W = W3; Wh = Wh3; Wl = Wl3; o = i - 786432; }
  float f = W[o];
  ushort h = f2bf(f);
  Wh[o] = h;
  Wl[o] = f2bf(f - bf2f(h));
}

// ---------------- feature transpose+split + fused column sumsq ----------------
__global__ __launch_bounds__(256)
void transpose_split(const float* __restrict__ F, ushort* __restrict__ FhT,
                     ushort* __restrict__ FlT, float* __restrict__ nrmsq) {
  __shared__ float tile[64][65];
  __shared__ float nsq[64];
  int b = blockIdx.z, d0 = blockIdx.y * 64, n0 = blockIdx.x * 64;
  const float* src = F + ((long)b * D_ + d0) * N_ + n0;
  int t = threadIdx.x;
  if (t < 64) nsq[t] = 0.f;
  int rr4 = t >> 4, c4 = (t & 15) * 4;
#pragma unroll
  for (int p = 0; p < 4; ++p) {
    int dr = p * 16 + rr4;
    float4 v = *(const float4*)(src + (long)dr * N_ + c4);
    tile[dr][c4 + 0] = v.x;
    tile[dr][c4 + 1] = v.y;
    tile[dr][c4 + 2] = v.z;
    tile[dr][c4 + 3] = v.w;
  }
  __syncthreads();
  int nlb = t >> 3, ds = (t & 7) * 8;
#pragma unroll
  for (int p = 0; p < 2; ++p) {
    int nl = p * 32 + nlb;
    sx8 hv, lv;
    float sq = 0.f;
#pragma unroll
    for (int j = 0; j < 8; ++j) {
      float f = tile[ds + j][nl];
      sq += f * f;
      ushort h = f2bf(f);
      hv[j] = (short)h;
      lv[j] = (short)f2bf(f - bf2f(h));
    }
    atomicAdd(&nsq[nl], sq);
    long o = ((long)b * N_ + n0 + nl) * D_ + d0 + ds;
    *(sx8*)(FhT + o) = hv;
    *(sx8*)(FlT + o) = lv;
  }
  __syncthreads();
  if (t < 64) atomicAdd(&nrmsq[(long)b * N_ + n0 + t], nsq[t]);
}

// ---------------- 128x128 split-bf16 MFMA GEMM (conv1/conv2) ----------------
__global__ __launch_bounds__(256)
void gemm_split_bf16(const ushort* __restrict__ Ah, const ushort* __restrict__ Al,
                     const ushort* __restrict__ BhT, const ushort* __restrict__ BlT,
                     float* __restrict__ C, const float* __restrict__ bias,
                     int N, int Kd, long sBT, long sC) {
  __shared__ ushort As[2][128][40];
  __shared__ ushort Bs[2][128][40];
  const int t = threadIdx.x;
  const int m0 = blockIdx.y * 128, n0 = blockIdx.x * 128;
  const long bo = (long)blockIdx.z * sBT;
  float* Cp = C + (long)blockIdx.z * sC;
  const int half = t >> 7, r = t & 127;
  const ushort* Asrc = (half ? Al : Ah) + (long)(m0 + r) * Kd;
  const ushort* Bsrc = (half ? BlT : BhT) + bo + (long)(n0 + r) * Kd;
  ushort* AsD = &As[half][r][0];
  ushort* BsD = &Bs[half][r][0];
  const int w = t >> 6, ln = t & 15, qd = (t & 63) >> 4;
  const int wm = w >> 1, wn = w & 1;

  fx4 acc[4][4];
#pragma unroll
  for (int i = 0; i < 4; ++i)
#pragma unroll
    for (int j = 0; j < 4; ++j) acc[i][j] = (fx4)0.f;

  for (int k0 = 0; k0 < Kd; k0 += 32) {
    uint4 a0 = *(const uint4*)(Asrc + k0);
    uint4 a1 = *(const uint4*)(Asrc + k0 + 8);
    uint4 a2 = *(const uint4*)(Asrc + k0 + 16);
    uint4 a3 = *(const uint4*)(Asrc + k0 + 24);
    uint4 b0 = *(const uint4*)(Bsrc + k0);
    uint4 b1 = *(const uint4*)(Bsrc + k0 + 8);
    uint4 b2 = *(const uint4*)(Bsrc + k0 + 16);
    uint4 b3 = *(const uint4*)(Bsrc + k0 + 24);
    __syncthreads();
    *(uint4*)(AsD + 0) = a0;
    *(uint4*)(AsD + 8) = a1;
    *(uint4*)(AsD + 16) = a2;
    *(uint4*)(AsD + 24) = a3;
    *(uint4*)(BsD + 0) = b0;
    *(uint4*)(BsD + 8) = b1;
    *(uint4*)(BsD + 16) = b2;
    *(uint4*)(BsD + 24) = b3;
    __syncthreads();
    sx8 ahf[4], alf[4], bhf[4], blf[4];
#pragma unroll
    for (int mt = 0; mt < 4; ++mt) {
      ahf[mt] = *(const sx8*)&As[0][wm * 64 + mt * 16 + ln][qd * 8];
      alf[mt] = *(const sx8*)&As[1][wm * 64 + mt * 16 + ln][qd * 8];
    }
#pragma unroll
    for (int nt = 0; nt < 4; ++nt) {
      bhf[nt] = *(const sx8*)&Bs[0][wn * 64 + nt * 16 + ln][qd * 8];
      blf[nt] = *(const sx8*)&Bs[1][wn * 64 + nt * 16 + ln][qd * 8];
    }
#pragma unroll
    for (int mt = 0; mt < 4; ++mt)
#pragma unroll
      for (int nt = 0; nt < 4; ++nt) {
        acc[mt][nt] = __builtin_amdgcn_mfma_f32_16x16x32_bf16(ahf[mt], bhf[nt], acc[mt][nt], 0, 0, 0);
        acc[mt][nt] = __builtin_amdgcn_mfma_f32_16x16x32_bf16(alf[mt], bhf[nt], acc[mt][nt], 0, 0, 0);
        acc[mt][nt] = __builtin_amdgcn_mfma_f32_16x16x32_bf16(ahf[mt], blf[nt], acc[mt][nt], 0, 0, 0);
      }
  }
#pragma unroll
  for (int mt = 0; mt < 4; ++mt) {
#pragma unroll
    for (int rr = 0; rr < 4; ++rr) {
      int row = m0 + wm * 64 + mt * 16 + qd * 4 + rr;
      float bb = bias[row];
#pragma unroll
      for (int nt = 0; nt < 4; ++nt) {
        int col = n0 + wn * 64 + nt * 16 + ln;
        Cp[(long)row * N + col] = acc[mt][nt][rr] + bb;
      }
    }
  }
}

// ================= M64 split-bf16 MFMA family =================

// --- variant bb: A pre-split [64][Kd], B pre-split transposed [Nc][Kd] (conv3) ---
__global__ __launch_bounds__(256)
void gemm64_bb(const ushort* __restrict__ Ah, const ushort* __restrict__ Al,
               const ushort* __restrict__ BhT, const ushort* __restrict__ BlT,
               float* __restrict__ C, const float* __restrict__ bias,
               int N, int Kd, long sBT, long sC) {
  __shared__ ushort As[2][64][40];
  __shared__ ushort Bs[2][128][40];
  const int t = threadIdx.x;
  const int n0 = blockIdx.x * 128;
  float* Cp = C + (long)blockIdx.z * sC;
  const int hB = t >> 7, rB = t & 127;
  const ushort* Bsrc = (hB ? BlT : BhT) + (long)blockIdx.z * sBT + (long)(n0 + rB) * Kd;
  ushort* BsD = &Bs[hB][rB][0];
  const bool doA = t < 128;
  const int hA = (t >> 6) & 1, rA = t & 63;
  const ushort* Asrc = (hA ? Al : Ah) + (long)rA * Kd;
  ushort* AsD = &As[hA][rA][0];
  const int w = t >> 6, ln = t & 15, qd = (t & 63) >> 4;
  const int wm = w >> 1, wn = w & 1;

  fx4 acc[2][4];
#pragma unroll
  for (int i = 0; i < 2; ++i)
#pragma unroll
    for (int j = 0; j < 4; ++j) acc[i][j] = (fx4)0.f;

  for (int k0 = 0; k0 < Kd; k0 += 32) {
    uint4 b0 = *(const uint4*)(Bsrc + k0);
    uint4 b1 = *(const uint4*)(Bsrc + k0 + 8);
    uint4 b2 = *(const uint4*)(Bsrc + k0 + 16);
    uint4 b3 = *(const uint4*)(Bsrc + k0 + 24);
    uint4 a0, a1, a2, a3;
    if (doA) {
      a0 = *(const uint4*)(Asrc + k0);
      a1 = *(const uint4*)(Asrc + k0 + 8);
      a2 = *(const uint4*)(Asrc + k0 + 16);
      a3 = *(const uint4*)(Asrc + k0 + 24);
    }
    __syncthreads();
    *(uint4*)(BsD + 0) = b0;
    *(uint4*)(BsD + 8) = b1;
    *(uint4*)(BsD + 16) = b2;
    *(uint4*)(BsD + 24) = b3;
    if (doA) {
      *(uint4*)(AsD + 0) = a0;
      *(uint4*)(AsD + 8) = a1;
      *(uint4*)(AsD + 16) = a2;
      *(uint4*)(AsD + 24) = a3;
    }
    __syncthreads();
    sx8 ahf[2], alf[2], bhf[4], blf[4];
#pragma unroll
    for (int mt = 0; mt < 2; ++mt) {
      ahf[mt] = *(const sx8*)&As[0][wm * 32 + mt * 16 + ln][qd * 8];
      alf[mt] = *(const sx8*)&As[1][wm * 32 + mt * 16 + ln][qd * 8];
    }
#pragma unroll
    for (int nt = 0; nt < 4; ++nt) {
      bhf[nt] = *(const sx8*)&Bs[0][wn * 64 + nt * 16 + ln][qd * 8];
      blf[nt] = *(const sx8*)&Bs[1][wn * 64 + nt * 16 + ln][qd * 8];
    }
#pragma unroll
    for (int mt = 0; mt < 2; ++mt)
#pragma unroll
      for (int nt = 0; nt < 4; ++nt) {
        acc[mt][nt] = __builtin_amdgcn_mfma_f32_16x16x32_bf16(ahf[mt], bhf[nt], acc[mt][nt], 0, 0, 0);
        acc[mt][nt] = __builtin_amdgcn_mfma_f32_16x16x32_bf16(alf[mt], bhf[nt], acc[mt][nt], 0, 0, 0);
        acc[mt][nt] = __builtin_amdgcn_mfma_f32_16x16x32_bf16(ahf[mt], blf[nt], acc[mt][nt], 0, 0, 0);
      }
  }
#pragma unroll
  for (int mt = 0; mt < 2; ++mt)
#pragma unroll
    for (int rr = 0; rr < 4; ++rr) {
      int row = wm * 32 + mt * 16 + qd * 4 + rr;
      float bb = bias[row];
#pragma unroll
      for (int nt = 0; nt < 4; ++nt) {
        int col = n0 + wn * 64 + nt * 16 + ln;
        Cp[(long)row * N + col] = acc[mt][nt][rr] + bb;
      }
    }
}

// --- variant bf: A pre-split [b][64][N_], B = f32 rows natural along Kd (mu_fea) ---
__global__ __launch_bounds__(256)
void gemm64_bf(const ushort* __restrict__ Ah, const ushort* __restrict__ Al,
               const float* __restrict__ Bf, float* __restrict__ Cacc) {
  __shared__ ushort As[2][64][40];
  __shared__ ushort Bs[2][128][40];
  const int t = threadIdx.x;
  const int nc0 = blockIdx.x * 128;
  const int kBeg = blockIdx.y * 1024;
  const int b = blockIdx.z;
  const int pc = t >> 7, rB = t & 127;
  const float* Bsrc = Bf + (long)b * D_ * N_ + (long)(nc0 + rB) * N_ + kBeg + pc * 16;
  const bool doA = t < 128;
  const int hA = (t >> 6) & 1, rA = t & 63;
  const ushort* Asrc = (hA ? Al : Ah) + (long)b * K_ * N_ + (long)rA * N_ + kBeg;
  ushort* AsD = &As[hA][rA][0];
  const int w = t >> 6, ln = t & 15, qd = (t & 63) >> 4;
  const int wm = w >> 1, wn = w & 1;

  fx4 acc[2][4];
#pragma unroll
  for (int i = 0; i < 2; ++i)
#pragma unroll
    for (int j = 0; j < 4; ++j) acc[i][j] = (fx4)0.f;

  for (int k0 = 0; k0 < 1024; k0 += 32) {
    float4 f0 = *(const float4*)(Bsrc + k0);
    float4 f1 = *(const float4*)(Bsrc + k0 + 4);
    float4 f2 = *(const float4*)(Bsrc + k0 + 8);
    float4 f3 = *(const float4*)(Bsrc + k0 + 12);
    uint4 a0, a1, a2, a3;
    if (doA) {
      a0 = *(const uint4*)(Asrc + k0);
      a1 = *(const uint4*)(Asrc + k0 + 8);
      a2 = *(const uint4*)(Asrc + k0 + 16);
      a3 = *(const uint4*)(Asrc + k0 + 24);
    }
    float fv[16] = {f0.x, f0.y, f0.z, f0.w, f1.x, f1.y, f1.z, f1.w,
                    f2.x, f2.y, f2.z, f2.w, f3.x, f3.y, f3.z, f3.w};
    sx8 hv0, hv1, lv0, lv1;
#pragma unroll
    for (int j = 0; j < 8; ++j) {
      ushort h = f2bf(fv[j]);
      hv0[j] = (short)h;
      lv0[j] = (short)f2bf(fv[j] - bf2f(h));
    }
#pragma unroll
    for (int j = 0; j < 8; ++j) {
      ushort h = f2bf(fv[8 + j]);
      hv1[j] = (short)h;
      lv1[j] = (short)f2bf(fv[8 + j] - bf2f(h));
    }
    __syncthreads();
    *(sx8*)&Bs[0][rB][pc * 16] = hv0;
    *(sx8*)&Bs[0][rB][pc * 16 + 8] = hv1;
    *(sx8*)&Bs[1][rB][pc * 16] = lv0;
    *(sx8*)&Bs[1][rB][pc * 16 + 8] = lv1;
    if (doA) {
      *(uint4*)(AsD + 0) = a0;
      *(uint4*)(AsD + 8) = a1;
      *(uint4*)(AsD + 16) = a2;
      *(uint4*)(AsD + 24) = a3;
    }
    __syncthreads();
    sx8 ahf[2], alf[2], bhf[4], blf[4];
#pragma unroll
    for (int mt = 0; mt < 2; ++mt) {
      ahf[mt] = *(const sx8*)&As[0][wm * 32 + mt * 16 + ln][qd * 8];
      alf[mt] = *(const sx8*)&As[1][wm * 32 + mt * 16 + ln][qd * 8];
    }
#pragma unroll
    for (int nt = 0; nt < 4; ++nt) {
      bhf[nt] = *(const sx8*)&Bs[0][wn * 64 + nt * 16 + ln][qd * 8];
      blf[nt] = *(const sx8*)&Bs[1][wn * 64 + nt * 16 + ln][qd * 8];
    }
#pragma unroll
    for (int mt = 0; mt < 2; ++mt)
#pragma unroll
      for (int nt = 0; nt < 4; ++nt) {
        acc[mt][nt] = __builtin_amdgcn_mfma_f32_16x16x32_bf16(ahf[mt], bhf[nt], acc[mt][nt], 0, 0, 0);
        acc[mt][nt] = __builtin_amdgcn_mfma_f32_16x16x32_bf16(alf[mt], bhf[nt], acc[mt][nt], 0, 0, 0);
        acc[mt][nt] = __builtin_amdgcn_mfma_f32_16x16x32_bf16(ahf[mt], blf[nt], acc[mt][nt], 0, 0, 0);
      }
  }
#pragma unroll
  for (int mt = 0; mt < 2; ++mt)
#pragma unroll
    for (int rr = 0; rr < 4; ++rr) {
      int row = wm * 32 + mt * 16 + qd * 4 + rr;
#pragma unroll
      for (int nt = 0; nt < 4; ++nt) {
        int col = nc0 + wn * 64 + nt * 16 + ln;
        atomicAdd(&Cacc[((long)b * K_ + row) * D_ + col], acc[mt][nt][rr]);
      }
    }
}

// --- variant bt: A pre-split [b][64][D_], B = f32 [D][N] transposed in LDS (cost_fea) ---
// epilogue reads raw column sumsq and computes rsqrt inline
__global__ __launch_bounds__(256)
void gemm64_bt(const ushort* __restrict__ Ah, const ushort* __restrict__ Al,
               const float* __restrict__ Bf, const float* __restrict__ nrmsq,
               float* __restrict__ cost) {
  __shared__ ushort As[2][64][40];
  __shared__ ushort Bs[2][128][40];
  __shared__ float Ft[32][132];
  const int t = threadIdx.x;
  const int n0 = blockIdx.x * 128;
  const int b = blockIdx.z;
  const float* Fsrc = Bf + (long)b * D_ * N_;
  const bool doA = t < 128;
  const int hA = (t >> 6) & 1, rA = t & 63;
  const ushort* Asrc = (hA ? Al : Ah) + (long)b * K_ * D_ + (long)rA * D_;
  ushort* AsD = &As[hA][rA][0];
  const int dr = t >> 3, cc = (t & 7) * 16;
  const int nl = t & 127, dh = t >> 7;
  const int w = t >> 6, ln = t & 15, qd = (t & 63) >> 4;
  const int wm = w >> 1, wn = w & 1;

  fx4 acc[2][4];
#pragma unroll
  for (int i = 0; i < 2; ++i)
#pragma unroll
    for (int j = 0; j < 4; ++j) acc[i][j] = (fx4)0.f;

  for (int k0 = 0; k0 < D_; k0 += 32) {
    float4 f0 = *(const float4*)(Fsrc + (long)(k0 + dr) * N_ + n0 + cc);
    float4 f1 = *(const float4*)(Fsrc + (long)(k0 + dr) * N_ + n0 + cc + 4);
    float4 f2 = *(const float4*)(Fsrc + (long)(k0 + dr) * N_ + n0 + cc + 8);
    float4 f3 = *(const float4*)(Fsrc + (long)(k0 + dr) * N_ + n0 + cc + 12);
    uint4 a0, a1, a2, a3;
    if (doA) {
      a0 = *(const uint4*)(Asrc + k0);
      a1 = *(const uint4*)(Asrc + k0 + 8);
      a2 = *(const uint4*)(Asrc + k0 + 16);
      a3 = *(const uint4*)(Asrc + k0 + 24);
    }
    __syncthreads();
    *(float4*)&Ft[dr][cc] = f0;
    *(float4*)&Ft[dr][cc + 4] = f1;
    *(float4*)&Ft[dr][cc + 8] = f2;
    *(float4*)&Ft[dr][cc + 12] = f3;
    if (doA) {
      *(uint4*)(AsD + 0) = a0;
      *(uint4*)(AsD + 8) = a1;
      *(uint4*)(AsD + 16) = a2;
      *(uint4*)(AsD + 24) = a3;
    }
    __syncthreads();
    float fv[16];
#pragma unroll
    for (int j = 0; j < 16; ++j) fv[j] = Ft[dh * 16 + j][nl];
    sx8 hv0, hv1, lv0, lv1;
#pragma unroll
    for (int j = 0; j < 8; ++j) {
      ushort h = f2bf(fv[j]);
      hv0[j] = (short)h;
      lv0[j] = (short)f2bf(fv[j] - bf2f(h));
    }
#pragma unroll
    for (int j = 0; j < 8; ++j) {
      ushort h = f2bf(fv[8 + j]);
      hv1[j] = (short)h;
      lv1[j] = (short)f2bf(fv[8 + j] - bf2f(h));
    }
    *(sx8*)&Bs[0][nl][dh * 16] = hv0;
    *(sx8*)&Bs[0][nl][dh * 16 + 8] = hv1;
    *(sx8*)&Bs[1][nl][dh * 16] = lv0;
    *(sx8*)&Bs[1][nl][dh * 16 + 8] = lv1;
    __syncthreads();
    sx8 ahf[2], alf[2], bhf[4], blf[4];
#pragma unroll
    for (int mt = 0; mt < 2; ++mt) {
      ahf[mt] = *(const sx8*)&As[0][wm * 32 + mt * 16 + ln][qd * 8];
      alf[mt] = *(const sx8*)&As[1][wm * 32 + mt * 16 + ln][qd * 8];
    }
#pragma unroll
    for (int nt = 0; nt < 4; ++nt) {
      bhf[nt] = *(const sx8*)&Bs[0][wn * 64 + nt * 16 + ln][qd * 8];
      blf[nt] = *(const sx8*)&Bs[1][wn * 64 + nt * 16 + ln][qd * 8];
    }
#pragma unroll
    for (int mt = 0; mt < 2; ++mt)
#pragma unroll
      for (int nt = 0; nt < 4; ++nt) {
        acc[mt][nt] = __builtin_amdgcn_mfma_f32_16x16x32_bf16(ahf[mt], bhf[nt], acc[mt][nt], 0, 0, 0);
        acc[mt][nt] = __builtin_amdgcn_mfma_f32_16x16x32_bf16(alf[mt], bhf[nt], acc[mt][nt], 0, 0, 0);
        acc[mt][nt] = __builtin_amdgcn_mfma_f32_16x16x32_bf16(ahf[mt], blf[nt], acc[mt][nt], 0, 0, 0);
      }
  }
#pragma unroll
  for (int nt = 0; nt < 4; ++nt) {
    int col = n0 + wn * 64 + nt * 16 + ln;
    float q = nrmsq[b * N_ + col];
    float iv = 1.f / fmaxf(sqrtf(q), 1e-12f);
#pragma unroll
    for (int mt = 0; mt < 2; ++mt)
#pragma unroll
      for (int rr = 0; rr < 4; ++rr) {
        int row = wm * 32 + mt * 16 + qd * 4 + rr;
        cost[((long)b * K_ + row) * N_ + col] = 2.f - 2.f * acc[mt][nt][rr] * iv;
      }
  }
}

// ---------------- BN stats ----------------
__global__ __launch_bounds__(256)
void bn_stats(const float* __restrict__ Y, const float* __restrict__ g,
              const float* __restrict__ be, float* __restrict__ scale,
              float* __restrict__ shift, int C) {
  int c = blockIdx.x;
  double s1 = 0.0, s2 = 0.0;
  for (int idx = threadIdx.x; idx < B_ * N_; idx += 256) {
    int b = idx >> 12, n = idx & (N_ - 1);
    float v = Y[((long)b * C + c) * N_ + n];
    s1 += v;
    s2 += (double)v * (double)v;
  }
  __shared__ double r1[256], r2[256];
  int tid = threadIdx.x;
  r1[tid] = s1; r2[tid] = s2;
  __syncthreads();
  for (int s = 128; s > 0; s >>= 1) {
    if (tid < s) { r1[tid] += r1[tid + s]; r2[tid] += r2[tid + s]; }
    __syncthreads();
  }
  if (tid == 0) {
    double m = r1[0] / (double)(B_ * N_);
    double var = r2[0] / (double)(B_ * N_) - m * m;
    float sc = (float)((double)g[c] / sqrt(var + 1e-5));
    scale[c] = sc;
    shift[c] = (float)((double)be[c] - m * (double)sc);
  }
}

// ---------------- BN+ReLU + transpose+split ----------------
__global__ __launch_bounds__(256)
void bn_relu_t(const float* __restrict__ Y, const float* __restrict__ scale,
               const float* __restrict__ shift, ushort* __restrict__ OhT,
               ushort* __restrict__ OlT) {
  __shared__ float tile[64][65];
  int b = blockIdx.z, h0 = blockIdx.y * 64, n0 = blockIdx.x * 64;
  const float* src = Y + ((long)b * H_ + h0) * N_ + n0;
  int t = threadIdx.x;
  int rr4 = t >> 4, c4 = (t & 15) * 4;
#pragma unroll
  for (int p = 0; p < 4; ++p) {
    int hl = p * 16 + rr4;
    float sc = scale[h0 + hl], sh = shift[h0 + hl];
    float4 v = *(const float4*)(src + (long)hl * N_ + c4);
    tile[hl][c4 + 0] = fmaxf(v.x * sc + sh, 0.f);
    tile[hl][c4 + 1] = fmaxf(v.y * sc + sh, 0.f);
    tile[hl][c4 + 2] = fmaxf(v.z * sc + sh, 0.f);
    tile[hl][c4 + 3] = fmaxf(v.w * sc + sh, 0.f);
  }
  __syncthreads();
  int nlb = t >> 3, hs = (t & 7) * 8;
#pragma unroll
  for (int p = 0; p < 2; ++p) {
    int nl = p * 32 + nlb;
    sx8 hv, lv;
#pragma unroll
    for (int j = 0; j < 8; ++j) {
      float f = tile[hs + j][nl];
      ushort h = f2bf(f);
      hv[j] = (short)h;
      lv[j] = (short)f2bf(f - bf2f(h));
    }
    long o = ((long)b * N_ + n0 + nl) * H_ + h0 + hs;
    *(sx8*)(OhT + o) = hv;
    *(sx8*)(OlT + o) = lv;
  }
}

// ---------------- softmax: score f32/bf16, logp [b][n][K] ----------------
__global__ __launch_bounds__(256)
void softmax_nk(const float* __restrict__ ls, float* __restrict__ scoreKN,
                ushort* __restrict__ sch, ushort* __restrict__ scl,
                float* __restrict__ logpNK, float* __restrict__ pi_raw) {
  __shared__ float L[64][65];
  __shared__ float ploc[64];
  int tid = threadIdx.x;
  if (tid < 64) ploc[tid] = 0.f;
  __syncthreads();
  int bi = blockIdx.x >> 4;
  int nb = (blockIdx.x & 15) * 256;
  int n = nb + tid;
  const float* x = ls + ((long)bi * K_) * N_ + n;
  float xv[64];
#pragma unroll
  for (int k = 0; k < 64; ++k) xv[k] = x[(long)k * N_];
  float mx = -1e30f;
#pragma unroll
  for (int k = 0; k < 64; ++k) mx = fmaxf(mx, xv[k]);
  float s = 0.f;
#pragma unroll
  for (int k = 0; k < 64; ++k) s += __expf(xv[k] - mx);
  float lg = __logf(s);
  float inv = 1.f / s;
#pragma unroll
  for (int k = 0; k < 64; ++k) {
    float sc = __expf(xv[k] - mx) * inv;
    long o = ((long)bi * K_ + k) * N_ + n;
    scoreKN[o] = sc;
    ushort h = f2bf(sc);
    sch[o] = h;
    scl[o] = f2bf(sc - bf2f(h));
    atomicAdd(&ploc[k], sc);
  }
  __syncthreads();
  if (tid < 64) atomicAdd(&pi_raw[bi * 64 + tid], ploc[tid]);
  int myw = tid >> 6, nl = tid & 63;
  int row = tid >> 2, ch = (tid & 3) * 16;
  for (int p = 0; p < 4; ++p) {
    __syncthreads();
    if (myw == p) {
#pragma unroll
      for (int k = 0; k < 64; ++k) L[nl][k] = xv[k] - mx - lg;
    }
    __syncthreads();
    float o0[16];
#pragma unroll
    for (int j = 0; j < 16; ++j) o0[j] = L[row][ch + j];
    float* dst = logpNK + ((long)bi * N_ + nb + p * 64 + row) * 64 + ch;
    *(float4*)(dst + 0) = make_float4(o0[0], o0[1], o0[2], o0[3]);
    *(float4*)(dst + 4) = make_float4(o0[4], o0[5], o0[6], o0[7]);
    *(float4*)(dst + 8) = make_float4(o0[8], o0[9], o0[10], o0[11]);
    *(float4*)(dst + 12) = make_float4(o0[12], o0[13], o0[14], o0[15]);
  }
}

// ---------------- mu_xyz ----------------
__global__ __launch_bounds__(64)
void mu_xyz_k(const float* __restrict__ scoreKN, const float* __restrict__ xyz,
              const float* __restrict__ pi_raw, float* __restrict__ mu,
              float* __restrict__ yn) {
  int k = blockIdx.x, b = blockIdx.y, t = threadIdx.x;
  const float* st = scoreKN + ((long)b * K_ + k) * N_;
  const float* xp = xyz + (long)b * 3 * N_;
  float a0 = 0, a1 = 0, a2 = 0;
  for (int n = t; n < N_; n += 64) {
    float s = st[n];
    a0 += s * xp[n];
    a1 += s * xp[N_ + n];
    a2 += s * xp[2 * N_ + n];
  }
  for (int off = 32; off > 0; off >>= 1) {
    a0 += __shfl_down(a0, off);
    a1 += __shfl_down(a1, off);
    a2 += __shfl_down(a2, off);
  }
  if (t == 0) {
    float p = fmaxf(pi_raw[b * K_ + k], 1e-4f);
    float m0 = a0 / p, m1 = a1 / p, m2 = a2 / p;
    mu[((long)b * 3 + 0) * K_ + k] = m0;
    mu[((long)b * 3 + 1) * K_ + k] = m1;
    mu[((long)b * 3 + 2) * K_ + k] = m2;
    yn[b * K_ + k] = m0 * m0 + m1 * m1 + m2 * m2;
  }
}

// ---------------- regularizers ----------------
__global__ __launch_bounds__(256)
void reg_xyz_k(const float* __restrict__ mu, float* __restrict__ out) {
  __shared__ float red[256];
  int b = blockIdx.x, tid = threadIdx.x;
  float acc = 0.f;
  for (int e = tid; e < 4096; e += 256) {
    int m = e >> 6, n2 = e & 63;
    float g = 0.f;
    for (int d = 0; d < 3; ++d)
      g += mu[((long)b * 3 + d) * K_ + m] * mu[((long)b * 3 + d) * K_ + n2];
    acc += fabsf(g - (m == n2 ? 1.f : 0.f));
  }
  float tot = block_reduce_sum256(acc, red);
  if (tid == 0) atomicAdd(out, tot * (1e-7f / 32768.f));
}

__global__ __launch_bounds__(256)
void reg_fea_k(const float* __restrict__ nT, float* __restrict__ out) {
  __shared__ float pm[1024];
  __shared__ float red[256];
  int m = blockIdx.x, b = blockIdx.y, tid = threadIdx.x;
  const float* base = nT + (long)b * K_ * D_;
  *(float4*)&pm[tid * 4] = *(const float4*)(base + (long)m * D_ + tid * 4);
  __syncthreads();
  int n2 = tid >> 2, q = tid & 3;
  const float* pn = base + (long)n2 * D_ + q * 256;
  const float* pml = &pm[q * 256];
  float g = 0.f;
#pragma unroll 8
  for (int d = 0; d < 256; d += 4) {
    float4 v = *(const float4*)(pn + d);
    g += v.x * pml[d] + v.y * pml[d + 1] + v.z * pml[d + 2] + v.w * pml[d + 3];
  }
  g += __shfl_down(g, 2);
  g += __shfl_down(g, 1);
  float acc = (q == 0) ? fabsf(g - (m == n2 ? 1.f : 0.f)) : 0.f;
  float tot = block_reduce_sum256(acc, red);
  if (tid == 0) atomicAdd(out, tot * (1e-4f / 32768.f));
}

// ---------------- mu_fea finalize ----------------
__global__ __launch_bounds__(256)
void mu_finalize(const float* __restrict__ muT_raw, const float* __restrict__ pi_raw,
                 float* __restrict__ n_muT, ushort* __restrict__ nmu_h,
                 ushort* __restrict__ nmu_l) {
  __shared__ float red[256];
  int k = blockIdx.x, b = blockIdx.y, tid = threadIdx.x;
  float p = fmaxf(pi_raw[b * K_ + k], 1e-4f);
  const float* src = muT_raw + ((long)b * K_ + k) * D_;
  float ss = 0.f;
  for (int d = tid; d < D_; d += 256) {
    float v = src[d] / p;
    ss += v * v;
  }
  float tot = block_reduce_sum256(ss, red);
  float inv = 1.f / fmaxf(sqrtf(tot), 1e-12f);
  long o = ((long)b * K_ + k) * D_;
  for (int d = tid; d < D_; d += 256) {
    float v = src[d] / p * inv;
    n_muT[o + d] = v;
    ushort h = f2bf(v);
    nmu_h[o + d] = h;
    nmu_l[o + d] = f2bf(v - bf2f(h));
  }
}

// ---------------- cooperative Sinkhorn v4: flag-based arrival (no RMW) ----------------
__global__ __launch_bounds__(256, 1)
void sinkhorn_coop(const float* __restrict__ cost_f, const float* __restrict__ xyz,
                   const float* __restrict__ mu, const float* __restrict__ yn,
                   const float* __restrict__ logpNK, float* __restrict__ out,
                   unsigned long long* __restrict__ partMS,
                   unsigned int* __restrict__ seq) {
  __shared__ float tile[4][64][68];
  __shared__ float vsh[64];
  __shared__ float wm[4][64];
  __shared__ float wsum[4][64];
  __shared__ float red[256];
  __shared__ float mub[4][64];
  const int tid = threadIdx.x;
  const int g = blockIdx.x & 15;
  const int s = blockIdx.x >> 4;
  const int w = tid >> 6, lane = tid & 63;
  const int i = s * 256 + tid;
  const int b = g & 7;
  const float eps = 1e-3f, ti = 1000.0f;
  const float lgp = -8.317766166719343f;   // -log(4096)
  const float lgq = -4.1588830833596715f;  // -log(64)

  float c[64];
  if (g < 8) {
    if (tid < 64) {
      mub[0][tid] = mu[(b * 3 + 0) * K_ + tid];
      mub[1][tid] = mu[(b * 3 + 1) * K_ + tid];
      mub[2][tid] = mu[(b * 3 + 2) * K_ + tid];
      mub[3][tid] = yn[b * K_ + tid];
      vsh[tid] = 0.f;
    }
    __syncthreads();
    float x0 = xyz[((long)b * 3 + 0) * N_ + i];
    float x1 = xyz[((long)b * 3 + 1) * N_ + i];
    float x2 = xyz[((long)b * 3 + 2) * N_ + i];
    float xn = x0 * x0 + x1 * x1 + x2 * x2;
#pragma unroll
    for (int j = 0; j < 64; ++j)
      c[j] = xn + mub[3][j] - 2.f * (x0 * mub[0][j] + x1 * mub[1][j] + x2 * mub[2][j]);
  } else {
    const float* C = cost_f + (long)b * K_ * N_;
#pragma unroll
    for (int j = 0; j < 64; ++j) c[j] = C[(long)j * N_ + i];
    if (tid < 64) vsh[tid] = 0.f;
    __syncthreads();
  }
  float u = 0.f;

  for (int it = 0; it < 25; ++it) {
    float tj[64];
#pragma unroll
    for (int j = 0; j < 64; ++j) tj[j] = vsh[j] - c[j];
    float dm = -1e30f;
#pragma unroll
    for (int j = 0; j < 64; ++j) dm = fmaxf(dm, tj[j]);
    float ssum = 0.f;
#pragma unroll
    for (int j = 0; j < 64; ++j) ssum += __expf((tj[j] - dm) * ti);
    u = eps * (lgp - ((u + dm) * ti + __logf(ssum))) + u;
#pragma unroll
    for (int j4 = 0; j4 < 16; ++j4) {
      float4 v4;
      v4.x = (u + tj[j4 * 4 + 0]) * ti;
      v4.y = (u + tj[j4 * 4 + 1]) * ti;
      v4.z = (u + tj[j4 * 4 + 2]) * ti;
      v4.w = (u + tj[j4 * 4 + 3]) * ti;
      *(float4*)&tile[w][lane][j4 * 4] = v4;
    }
    __syncthreads();
    float M = -1e30f, S = 0.f;
#pragma unroll
    for (int r = 0; r < 64; ++r) {
      float a = tile[w][r][lane];
      M = fmaxf(M, a);
      S += __expf(a - lgp);
    }
    wm[w][lane] = M;
    wsum[w][lane] = S;
    __syncthreads();
    int buf = it & 1;
    if (tid < 64) {
      float Mb = fmaxf(fmaxf(wm[0][tid], wm[1][tid]), fmaxf(wm[2][tid], wm[3][tid]));
      float Sb = wsum[0][tid] + wsum[1][tid] + wsum[2][tid] + wsum[3][tid];
      unsigned long long pk =
          ((unsigned long long)__float_as_uint(Sb) << 32) | (unsigned long long)__float_as_uint(Mb);
      long idx = (((long)buf * 16 + g) * 16 + s) * 64 + tid;
      __hip_atomic_store(&partMS[idx], pk, __ATOMIC_RELAXED, __HIP_MEMORY_SCOPE_AGENT);
    }
    __syncthreads();  // drains all partial stores (barrier implies vmcnt(0))
    unsigned target = (unsigned)(it + 1);
    if (tid == 0)
      __hip_atomic_store(&seq[((long)g * 16 + s) * 32], target, __ATOMIC_RELEASE,
                         __HIP_MEMORY_SCOPE_AGENT);
    // lanes 0..15 of wave 0 poll the 16 slice flags in parallel (no RMW)
    if (tid < 16) {
      while (__hip_atomic_load(&seq[((long)g * 16 + tid) * 32], __ATOMIC_ACQUIRE,
                               __HIP_MEMORY_SCOPE_AGENT) < target)
        __builtin_amdgcn_s_sleep(1);
    }
    __syncthreads();
    if (tid < 64) {
      long base = (((long)buf * 16 + g) * 16) * 64 + tid;
      float M2 = -1e30f, S2 = 0.f;
#pragma unroll
      for (int p = 0; p < 16; ++p) {
        unsigned long long v =
            __hip_atomic_load(&partMS[base + (long)p * 64], __ATOMIC_RELAXED, __HIP_MEMORY_SCOPE_AGENT);
        M2 = fmaxf(M2, __uint_as_float((unsigned)v));
        S2 += __uint_as_float((unsigned)(v >> 32));
      }
      float lsec = fmaxf(M2, lgp + __logf(S2));
      vsh[tid] = eps * (lgq - lsec) + vsh[tid];
    }
    __syncthreads();
  }

  // fused loss
  const float* lp = logpNK + ((long)b * N_ + i) * 64;
  float part = 0.f;
#pragma unroll
  for (int j = 0; j < 64; ++j)
    part += __expf((u + vsh[j] - c[j]) * ti) * lp[j];
  red[tid] = part;
  __syncthreads();
  for (int st2 = 128; st2 > 0; st2 >>= 1) {
    if (tid < st2) red[tid] += red[tid + st2];
    __syncthreads();
  }
  if (tid == 0) atomicAdd(out, -red[0] / (float)B_);
}

// ---------------- launch ----------------
extern "C" void kernel_launch(void* const* d_in, const int* in_sizes, int n_in,
                              void* d_out, int out_size, void* d_ws, size_t ws_size,
                              hipStream_t stream) {
  const float* feature = (const float*)d_in[0];
  const float* xyz = (const float*)d_in[1];
  const float* w1 = (const float*)d_in[2];
  const float* b1 = (const float*)d_in[3];
  const float* g1 = (const float*)d_in[4];
  const float* be1 = (const float*)d_in[5];
  const float* w2 = (const float*)d_in[6];
  const float* b2 = (const float*)d_in[7];
  const float* g2 = (const float*)d_in[8];
  const float* be2 = (const float*)d_in[9];
  const float* w3 = (const float*)d_in[10];
  const float* b3 = (const float*)d_in[11];
  float* out = (float*)d_out;
  float* ws = (float*)d_ws;

  const long RSZ = 16777216L;
  float* regA = ws;
  float* regB1 = ws + RSZ;
  float* regB2 = ws + 2 * RSZ;
  float* sm = ws + 3 * RSZ;

  ushort* FhT = (ushort*)regB1;
  ushort* FlT = (ushort*)regB2;
  float* h1raw = regA;
  ushort* h1hT = (ushort*)regB1;
  ushort* h1lT = (ushort*)regB1 + RSZ;
  float* h2 = regB2;
  ushort* h2hT = (ushort*)regB1;
  ushort* h2lT = (ushort*)regB1 + RSZ;
  const long sz = (long)B_ * N_ * K_;
  float* log_score = regA;
  float* score_KN = regA + sz;
  float* logpNK = regA + 2 * sz;
  float* cost_f = regA + 3 * sz;
  ushort* sc_h = (ushort*)(regA + 4 * sz);
  ushort* sc_l = (ushort*)(regA + 4 * sz) + sz;

  ushort* Wh1 = (ushort*)sm; sm += 262144;
  ushort* Wl1 = (ushort*)sm; sm += 262144;
  ushort* Wh2 = (ushort*)sm; sm += 131072;
  ushort* Wl2 = (ushort*)sm; sm += 131072;
  ushort* Wh3 = (ushort*)sm; sm += 16384;
  ushort* Wl3 = (ushort*)sm; sm += 16384;
  float* muT_raw = sm; sm += (long)B_ * K_ * D_;
  float* n_muT = sm;   sm += (long)B_ * K_ * D_;
  ushort* nmu_h = (ushort*)sm; sm += 262144;
  ushort* nmu_l = (ushort*)sm; sm += 262144;
  unsigned long long* partMS = (unsigned long long*)sm; sm += 2 * 16 * 16 * 64 * 2;
  unsigned int* seq = (unsigned int*)sm; sm += 16 * 16 * 32;
  float* nrmsq = sm; sm += (long)B_ * N_;
  float* mu_x = sm;   sm += 2048;
  float* yn = sm;     sm += 512;
  float* pi_raw = sm; sm += 512;
  float* sc1 = sm; sm += 512;
  float* sh1 = sm; sm += 512;
  float* sc2 = sm; sm += 512;
  float* sh2 = sm; sm += 512;

  hipMemsetAsync(d_out, 0, sizeof(float) * out_size, stream);
  hipMemsetAsync(pi_raw, 0, 512 * sizeof(float), stream);
  hipMemsetAsync(seq, 0, 16 * 16 * 32 * sizeof(unsigned int), stream);
  hipMemsetAsync(muT_raw, 0, (long)B_ * K_ * D_ * sizeof(float), stream);
  hipMemsetAsync(nrmsq, 0, (long)B_ * N_ * sizeof(float), stream);

  split_w3<<<3200, 256, 0, stream>>>(w1, w2, w3, Wh1, Wl1, Wh2, Wl2, Wh3, Wl3);
  {
    dim3 g(N_ / 64, D_ / 64, B_);
    transpose_split<<<g, 256, 0, stream>>>(feature, FhT, FlT, nrmsq);
  }
  // conv1
  {
    dim3 g(N_ / 128, H_ / 128, B_);
    gemm_split_bf16<<<g, 256, 0, stream>>>(Wh1, Wl1, FhT, FlT, h1raw, b1,
                                           N_, D_, (long)N_ * D_, (long)H_ * N_);
  }
  bn_stats<<<H_, 256, 0, stream>>>(h1raw, g1, be1, sc1, sh1, H_);
  {
    dim3 g(N_ / 64, H_ / 64, B_);
    bn_relu_t<<<g, 256, 0, stream>>>(h1raw, sc1, sh1, h1hT, h1lT);
  }
  // conv2
  {
    dim3 g(N_ / 128, H_ / 128, B_);
    gemm_split_bf16<<<g, 256, 0, stream>>>(Wh2, Wl2, h1hT, h1lT, h2, b2,
                                           N_, H_, (long)N_ * H_, (long)H_ * N_);
  }
  bn_stats<<<H_, 256, 0, stream>>>(h2, g2, be2, sc2, sh2, H_);
  {
    dim3 g(N_ / 64, H_ / 64, B_);
    bn_relu_t<<<g, 256, 0, stream>>>(h2, sc2, sh2, h2hT, h2lT);
  }
  // conv3
  {
    dim3 g(N_ / 128, 1, B_);
    gemm64_bb<<<g, 256, 0, stream>>>(Wh3, Wl3, h2hT, h2lT, log_score, b3,
                                     N_, H_, (long)N_ * H_, (long)K_ * N_);
  }
  softmax_nk<<<B_ * N_ / 256, 256, 0, stream>>>(log_score, score_KN, sc_h, sc_l,
                                                logpNK, pi_raw);
  {
    dim3 g(K_, B_);
    mu_xyz_k<<<g, 64, 0, stream>>>(score_KN, xyz, pi_raw, mu_x, yn);
  }
  reg_xyz_k<<<B_, 256, 0, stream>>>(mu_x, out);
  // mu_fea
  {
    dim3 g(D_ / 128, 4, B_);
    gemm64_bf<<<g, 256, 0, stream>>>(sc_h, sc_l, feature, muT_raw);
  }
  {
    dim3 g(K_, B_);
    mu_finalize<<<g, 256, 0, stream>>>(muT_raw, pi_raw, n_muT, nmu_h, nmu_l);
  }
  {
    dim3 g(K_, B_);
    reg_fea_k<<<g, 256, 0, stream>>>(n_muT, out);
  }
  // cost_fea (inline rsqrt from raw sumsq)
  {
    dim3 g(N_ / 128, 1, B_);
    gemm64_bt<<<g, 256, 0, stream>>>(nmu_h, nmu_l, feature, nrmsq, cost_f);
  }
  // cooperative Sinkhorn + fused loss
  {
    void* kargs[] = {(void*)&cost_f, (void*)&xyz, (void*)&mu_x, (void*)&yn,
                     (void*)&logpNK, (void*)&out, (void*)&partMS, (void*)&seq};
    hipLaunchCooperativeKernel((const void*)sinkhorn_coop, dim3(256), dim3(256),
                               kargs, 0, stream);
  }
}

// Round 9
// 1075.728 us; speedup vs baseline: 1.1049x; 1.1049x over previous
//
#include <hip/hip_runtime.h>
#include <math.h>

#define B_ 8
#define D_ 1024
#define N_ 4096
#define K_ 64
#define H_ 512

typedef short sx8 __attribute__((ext_vector_type(8)));
typedef float fx4 __attribute__((ext_vector_type(4)));

// ---------------- helpers ----------------
__device__ __forceinline__ float block_reduce_sum256(float v, float* sm) {
  int tid = threadIdx.x;
  sm[tid] = v;
  __syncthreads();
  for (int s = 128; s > 0; s >>= 1) {
    if (tid < s) sm[tid] += sm[tid + s];
    __syncthreads();
  }
  float r = sm[0];
  __syncthreads();
  return r;
}

__device__ __forceinline__ ushort f2bf(float f) {
  unsigned u = __float_as_uint(f);
  unsigned r = (u + 0x7fffu + ((u >> 16) & 1u)) >> 16;
  return (ushort)r;
}
__device__ __forceinline__ float bf2f(ushort h) {
  return __uint_as_float(((unsigned)h) << 16);
}

// ---------------- fused weight split ----------------
__global__ __launch_bounds__(256)
void split_w3(const float* __restrict__ W1, const float* __restrict__ W2,
              const float* __restrict__ W3, ushort* __restrict__ Wh1,
              ushort* __restrict__ Wl1, ushort* __restrict__ Wh2,
              ushort* __restrict__ Wl2, ushort* __restrict__ Wh3,
              ushort* __restrict__ Wl3) {
  int i = blockIdx.x * 256 + threadIdx.x;
  const float* W;
  ushort *Wh, *Wl;
  int o;
  if (i < 524288) { W = W1; Wh = Wh1; Wl = Wl1; o = i; }
  else if (i < 786432) { W = W2; Wh = Wh2; Wl = Wl2; o = i - 524288; }
  else { W = W3; Wh = Wh3; Wl = Wl3; o = i - 786432; }
  float f = W[o];
  ushort h = f2bf(f);
  Wh[o] = h;
  Wl[o] = f2bf(f - bf2f(h));
}

// ---------------- conv_bt128: M=128/block split-bf16 MFMA GEMM ----------------
// A pre-split bf16 [M][Kd]; B = f32 [Kd][N] staged via LDS transpose+convert.
// Optional: BN(scale,shift)+ReLU fused into B staging; row stats (sum,sumsq) of
// C into rs/rss atomics; column sumsq of raw B into nrm (gated blockIdx.y==0).
__global__ __launch_bounds__(256)
void conv_bt128(const ushort* __restrict__ Ah, const ushort* __restrict__ Al,
                const float* __restrict__ Bf, const float* __restrict__ scale,
                const float* __restrict__ shift, float* __restrict__ C,
                const float* __restrict__ bias, float* __restrict__ rs,
                float* __restrict__ rss, float* __restrict__ nrm,
                int Kd, long sB, long sC) {
  __shared__ ushort As[2][128][40];
  __shared__ ushort Bs[2][128][40];
  __shared__ float Ft[32][132];
  __shared__ float scb[32], shb[32];
  __shared__ float rs_l[128], rss_l[128];
  const int t = threadIdx.x;
  const int n0 = blockIdx.x * 128;
  const int m0 = blockIdx.y * 128;
  const int b = blockIdx.z;
  const float* Fsrc = Bf + (long)b * sB;
  float* Cp = C + (long)b * sC;
  const int half = t >> 7, rA = t & 127;
  const ushort* Asrc = (half ? Al : Ah) + (long)(m0 + rA) * Kd;
  ushort* AsD = &As[half][rA][0];
  const int dr = t >> 3, cc = (t & 7) * 16;
  const int nl = t & 127, dh = t >> 7;
  const int w = t >> 6, ln = t & 15, qd = (t & 63) >> 4;
  const int wm = w >> 1, wn = w & 1;
  if (t < 128) { rs_l[t] = 0.f; rss_l[t] = 0.f; }
  float nsq = 0.f;

  fx4 acc[4][4];
#pragma unroll
  for (int i = 0; i < 4; ++i)
#pragma unroll
    for (int j = 0; j < 4; ++j) acc[i][j] = (fx4)0.f;

  for (int k0 = 0; k0 < Kd; k0 += 32) {
    float4 f0 = *(const float4*)(Fsrc + (long)(k0 + dr) * N_ + n0 + cc);
    float4 f1 = *(const float4*)(Fsrc + (long)(k0 + dr) * N_ + n0 + cc + 4);
    float4 f2 = *(const float4*)(Fsrc + (long)(k0 + dr) * N_ + n0 + cc + 8);
    float4 f3 = *(const float4*)(Fsrc + (long)(k0 + dr) * N_ + n0 + cc + 12);
    uint4 a0 = *(const uint4*)(Asrc + k0);
    uint4 a1 = *(const uint4*)(Asrc + k0 + 8);
    uint4 a2 = *(const uint4*)(Asrc + k0 + 16);
    uint4 a3 = *(const uint4*)(Asrc + k0 + 24);
    __syncthreads();  // prev iter fragment/Ft reads done
    *(float4*)&Ft[dr][cc] = f0;
    *(float4*)&Ft[dr][cc + 4] = f1;
    *(float4*)&Ft[dr][cc + 8] = f2;
    *(float4*)&Ft[dr][cc + 12] = f3;
    *(uint4*)(AsD + 0) = a0;
    *(uint4*)(AsD + 8) = a1;
    *(uint4*)(AsD + 16) = a2;
    *(uint4*)(AsD + 24) = a3;
    if (t < 32) {
      scb[t] = scale ? scale[k0 + t] : 1.f;
      shb[t] = scale ? shift[k0 + t] : 0.f;
    }
    __syncthreads();
    // transpose-convert: thread owns column nl, d-window dh*16..+16
    float fv[16];
#pragma unroll
    for (int j = 0; j < 16; ++j) {
      float v = Ft[dh * 16 + j][nl];
      if (scale) v = fmaxf(v * scb[dh * 16 + j] + shb[dh * 16 + j], 0.f);
      fv[j] = v;
      nsq += v * v;
    }
    sx8 hv0, hv1, lv0, lv1;
#pragma unroll
    for (int j = 0; j < 8; ++j) {
      ushort h = f2bf(fv[j]);
      hv0[j] = (short)h;
      lv0[j] = (short)f2bf(fv[j] - bf2f(h));
    }
#pragma unroll
    for (int j = 0; j < 8; ++j) {
      ushort h = f2bf(fv[8 + j]);
      hv1[j] = (short)h;
      lv1[j] = (short)f2bf(fv[8 + j] - bf2f(h));
    }
    *(sx8*)&Bs[0][nl][dh * 16] = hv0;
    *(sx8*)&Bs[0][nl][dh * 16 + 8] = hv1;
    *(sx8*)&Bs[1][nl][dh * 16] = lv0;
    *(sx8*)&Bs[1][nl][dh * 16 + 8] = lv1;
    __syncthreads();
    sx8 ahf[4], alf[4], bhf[4], blf[4];
#pragma unroll
    for (int mt = 0; mt < 4; ++mt) {
      ahf[mt] = *(const sx8*)&As[0][wm * 64 + mt * 16 + ln][qd * 8];
      alf[mt] = *(const sx8*)&As[1][wm * 64 + mt * 16 + ln][qd * 8];
    }
#pragma unroll
    for (int nt = 0; nt < 4; ++nt) {
      bhf[nt] = *(const sx8*)&Bs[0][wn * 64 + nt * 16 + ln][qd * 8];
      blf[nt] = *(const sx8*)&Bs[1][wn * 64 + nt * 16 + ln][qd * 8];
    }
#pragma unroll
    for (int mt = 0; mt < 4; ++mt)
#pragma unroll
      for (int nt = 0; nt < 4; ++nt) {
        acc[mt][nt] = __builtin_amdgcn_mfma_f32_16x16x32_bf16(ahf[mt], bhf[nt], acc[mt][nt], 0, 0, 0);
        acc[mt][nt] = __builtin_amdgcn_mfma_f32_16x16x32_bf16(alf[mt], bhf[nt], acc[mt][nt], 0, 0, 0);
        acc[mt][nt] = __builtin_amdgcn_mfma_f32_16x16x32_bf16(ahf[mt], blf[nt], acc[mt][nt], 0, 0, 0);
      }
  }
  // epilogue: write C (+bias), accumulate BN row stats
#pragma unroll
  for (int mt = 0; mt < 4; ++mt) {
#pragma unroll
    for (int rr = 0; rr < 4; ++rr) {
      int rloc = wm * 64 + mt * 16 + qd * 4 + rr;
      int row = m0 + rloc;
      float bb = bias[row];
      float s1 = 0.f, s2 = 0.f;
#pragma unroll
      for (int nt = 0; nt < 4; ++nt) {
        int col = n0 + wn * 64 + nt * 16 + ln;
        float y = acc[mt][nt][rr] + bb;
        Cp[(long)row * N_ + col] = y;
        s1 += y;
        s2 += y * y;
      }
      if (rs) {
#pragma unroll
        for (int m = 1; m < 16; m <<= 1) {
          s1 += __shfl_xor(s1, m);
          s2 += __shfl_xor(s2, m);
        }
        if (ln == 0) {
          atomicAdd(&rs_l[rloc], s1);
          atomicAdd(&rss_l[rloc], s2);
        }
      }
    }
  }
  if (nrm && blockIdx.y == 0)
    atomicAdd(&nrm[(long)b * N_ + n0 + nl], nsq);
  if (rs) {
    __syncthreads();
    if (t < 128) {
      atomicAdd(&rs[m0 + t], rs_l[t]);
      atomicAdd(&rss[m0 + t], rss_l[t]);
    }
  }
}

// ---------------- bn_fin: stats -> folded scale/shift ----------------
__global__ void bn_fin(const float* __restrict__ rs, const float* __restrict__ rss,
                       const float* __restrict__ g, const float* __restrict__ be,
                       float* __restrict__ sc, float* __restrict__ sh) {
  int c = blockIdx.x * 256 + threadIdx.x;
  if (c < H_) {
    float inv = 1.f / (float)(B_ * N_);
    float m = rs[c] * inv;
    float var = rss[c] * inv - m * m;
    float s = g[c] * rsqrtf(var + 1e-5f);
    sc[c] = s;
    sh[c] = be[c] - m * s;
  }
}

// ---------------- conv64_bn: conv3 (M=64, BN2-fused B staging) ----------------
__global__ __launch_bounds__(256)
void conv64_bn(const ushort* __restrict__ Ah, const ushort* __restrict__ Al,
               const float* __restrict__ Bf, const float* __restrict__ scale,
               const float* __restrict__ shift, float* __restrict__ C,
               const float* __restrict__ bias, int Kd, long sB, long sC) {
  __shared__ ushort As[2][64][40];
  __shared__ ushort Bs[2][128][40];
  __shared__ float Ft[32][132];
  __shared__ float scb[32], shb[32];
  const int t = threadIdx.x;
  const int n0 = blockIdx.x * 128;
  const int b = blockIdx.z;
  const float* Fsrc = Bf + (long)b * sB;
  float* Cp = C + (long)b * sC;
  const bool doA = t < 128;
  const int hA = (t >> 6) & 1, rA = t & 63;
  const ushort* Asrc = (hA ? Al : Ah) + (long)rA * Kd;
  ushort* AsD = &As[hA][rA][0];
  const int dr = t >> 3, cc = (t & 7) * 16;
  const int nl = t & 127, dh = t >> 7;
  const int w = t >> 6, ln = t & 15, qd = (t & 63) >> 4;
  const int wm = w >> 1, wn = w & 1;

  fx4 acc[2][4];
#pragma unroll
  for (int i = 0; i < 2; ++i)
#pragma unroll
    for (int j = 0; j < 4; ++j) acc[i][j] = (fx4)0.f;

  for (int k0 = 0; k0 < Kd; k0 += 32) {
    float4 f0 = *(const float4*)(Fsrc + (long)(k0 + dr) * N_ + n0 + cc);
    float4 f1 = *(const float4*)(Fsrc + (long)(k0 + dr) * N_ + n0 + cc + 4);
    float4 f2 = *(const float4*)(Fsrc + (long)(k0 + dr) * N_ + n0 + cc + 8);
    float4 f3 = *(const float4*)(Fsrc + (long)(k0 + dr) * N_ + n0 + cc + 12);
    uint4 a0, a1, a2, a3;
    if (doA) {
      a0 = *(const uint4*)(Asrc + k0);
      a1 = *(const uint4*)(Asrc + k0 + 8);
      a2 = *(const uint4*)(Asrc + k0 + 16);
      a3 = *(const uint4*)(Asrc + k0 + 24);
    }
    __syncthreads();
    *(float4*)&Ft[dr][cc] = f0;
    *(float4*)&Ft[dr][cc + 4] = f1;
    *(float4*)&Ft[dr][cc + 8] = f2;
    *(float4*)&Ft[dr][cc + 12] = f3;
    if (doA) {
      *(uint4*)(AsD + 0) = a0;
      *(uint4*)(AsD + 8) = a1;
      *(uint4*)(AsD + 16) = a2;
      *(uint4*)(AsD + 24) = a3;
    }
    if (t < 32) {
      scb[t] = scale[k0 + t];
      shb[t] = shift[k0 + t];
    }
    __syncthreads();
    float fv[16];
#pragma unroll
    for (int j = 0; j < 16; ++j) {
      float v = Ft[dh * 16 + j][nl];
      fv[j] = fmaxf(v * scb[dh * 16 + j] + shb[dh * 16 + j], 0.f);
    }
    sx8 hv0, hv1, lv0, lv1;
#pragma unroll
    for (int j = 0; j < 8; ++j) {
      ushort h = f2bf(fv[j]);
      hv0[j] = (short)h;
      lv0[j] = (short)f2bf(fv[j] - bf2f(h));
    }
#pragma unroll
    for (int j = 0; j < 8; ++j) {
      ushort h = f2bf(fv[8 + j]);
      hv1[j] = (short)h;
      lv1[j] = (short)f2bf(fv[8 + j] - bf2f(h));
    }
    *(sx8*)&Bs[0][nl][dh * 16] = hv0;
    *(sx8*)&Bs[0][nl][dh * 16 + 8] = hv1;
    *(sx8*)&Bs[1][nl][dh * 16] = lv0;
    *(sx8*)&Bs[1][nl][dh * 16 + 8] = lv1;
    __syncthreads();
    sx8 ahf[2], alf[2], bhf[4], blf[4];
#pragma unroll
    for (int mt = 0; mt < 2; ++mt) {
      ahf[mt] = *(const sx8*)&As[0][wm * 32 + mt * 16 + ln][qd * 8];
      alf[mt] = *(const sx8*)&As[1][wm * 32 + mt * 16 + ln][qd * 8];
    }
#pragma unroll
    for (int nt = 0; nt < 4; ++nt) {
      bhf[nt] = *(const sx8*)&Bs[0][wn * 64 + nt * 16 + ln][qd * 8];
      blf[nt] = *(const sx8*)&Bs[1][wn * 64 + nt * 16 + ln][qd * 8];
    }
#pragma unroll
    for (int mt = 0; mt < 2; ++mt)
#pragma unroll
      for (int nt = 0; nt < 4; ++nt) {
        acc[mt][nt] = __builtin_amdgcn_mfma_f32_16x16x32_bf16(ahf[mt], bhf[nt], acc[mt][nt], 0, 0, 0);
        acc[mt][nt] = __builtin_amdgcn_mfma_f32_16x16x32_bf16(alf[mt], bhf[nt], acc[mt][nt], 0, 0, 0);
        acc[mt][nt] = __builtin_amdgcn_mfma_f32_16x16x32_bf16(ahf[mt], blf[nt], acc[mt][nt], 0, 0, 0);
      }
  }
#pragma unroll
  for (int mt = 0; mt < 2; ++mt)
#pragma unroll
    for (int rr = 0; rr < 4; ++rr) {
      int row = wm * 32 + mt * 16 + qd * 4 + rr;
      float bb = bias[row];
#pragma unroll
      for (int nt = 0; nt < 4; ++nt) {
        int col = n0 + wn * 64 + nt * 16 + ln;
        Cp[(long)row * N_ + col] = acc[mt][nt][rr] + bb;
      }
    }
}

// --- variant bf: A pre-split [b][64][N_], B = f32 rows natural along Kd (mu_fea) ---
__global__ __launch_bounds__(256)
void gemm64_bf(const ushort* __restrict__ Ah, const ushort* __restrict__ Al,
               const float* __restrict__ Bf, float* __restrict__ Cacc) {
  __shared__ ushort As[2][64][40];
  __shared__ ushort Bs[2][128][40];
  const int t = threadIdx.x;
  const int nc0 = blockIdx.x * 128;
  const int kBeg = blockIdx.y * 1024;
  const int b = blockIdx.z;
  const int pc = t >> 7, rB = t & 127;
  const float* Bsrc = Bf + (long)b * D_ * N_ + (long)(nc0 + rB) * N_ + kBeg + pc * 16;
  const bool doA = t < 128;
  const int hA = (t >> 6) & 1, rA = t & 63;
  const ushort* Asrc = (hA ? Al : Ah) + (long)b * K_ * N_ + (long)rA * N_ + kBeg;
  ushort* AsD = &As[hA][rA][0];
  const int w = t >> 6, ln = t & 15, qd = (t & 63) >> 4;
  const int wm = w >> 1, wn = w & 1;

  fx4 acc[2][4];
#pragma unroll
  for (int i = 0; i < 2; ++i)
#pragma unroll
    for (int j = 0; j < 4; ++j) acc[i][j] = (fx4)0.f;

  for (int k0 = 0; k0 < 1024; k0 += 32) {
    float4 f0 = *(const float4*)(Bsrc + k0);
    float4 f1 = *(const float4*)(Bsrc + k0 + 4);
    float4 f2 = *(const float4*)(Bsrc + k0 + 8);
    float4 f3 = *(const float4*)(Bsrc + k0 + 12);
    uint4 a0, a1, a2, a3;
    if (doA) {
      a0 = *(const uint4*)(Asrc + k0);
      a1 = *(const uint4*)(Asrc + k0 + 8);
      a2 = *(const uint4*)(Asrc + k0 + 16);
      a3 = *(const uint4*)(Asrc + k0 + 24);
    }
    float fv[16] = {f0.x, f0.y, f0.z, f0.w, f1.x, f1.y, f1.z, f1.w,
                    f2.x, f2.y, f2.z, f2.w, f3.x, f3.y, f3.z, f3.w};
    sx8 hv0, hv1, lv0, lv1;
#pragma unroll
    for (int j = 0; j < 8; ++j) {
      ushort h = f2bf(fv[j]);
      hv0[j] = (short)h;
      lv0[j] = (short)f2bf(fv[j] - bf2f(h));
    }
#pragma unroll
    for (int j = 0; j < 8; ++j) {
      ushort h = f2bf(fv[8 + j]);
      hv1[j] = (short)h;
      lv1[j] = (short)f2bf(fv[8 + j] - bf2f(h));
    }
    __syncthreads();
    *(sx8*)&Bs[0][rB][pc * 16] = hv0;
    *(sx8*)&Bs[0][rB][pc * 16 + 8] = hv1;
    *(sx8*)&Bs[1][rB][pc * 16] = lv0;
    *(sx8*)&Bs[1][rB][pc * 16 + 8] = lv1;
    if (doA) {
      *(uint4*)(AsD + 0) = a0;
      *(uint4*)(AsD + 8) = a1;
      *(uint4*)(AsD + 16) = a2;
      *(uint4*)(AsD + 24) = a3;
    }
    __syncthreads();
    sx8 ahf[2], alf[2], bhf[4], blf[4];
#pragma unroll
    for (int mt = 0; mt < 2; ++mt) {
      ahf[mt] = *(const sx8*)&As[0][wm * 32 + mt * 16 + ln][qd * 8];
      alf[mt] = *(const sx8*)&As[1][wm * 32 + mt * 16 + ln][qd * 8];
    }
#pragma unroll
    for (int nt = 0; nt < 4; ++nt) {
      bhf[nt] = *(const sx8*)&Bs[0][wn * 64 + nt * 16 + ln][qd * 8];
      blf[nt] = *(const sx8*)&Bs[1][wn * 64 + nt * 16 + ln][qd * 8];
    }
#pragma unroll
    for (int mt = 0; mt < 2; ++mt)
#pragma unroll
      for (int nt = 0; nt < 4; ++nt) {
        acc[mt][nt] = __builtin_amdgcn_mfma_f32_16x16x32_bf16(ahf[mt], bhf[nt], acc[mt][nt], 0, 0, 0);
        acc[mt][nt] = __builtin_amdgcn_mfma_f32_16x16x32_bf16(alf[mt], bhf[nt], acc[mt][nt], 0, 0, 0);
        acc[mt][nt] = __builtin_amdgcn_mfma_f32_16x16x32_bf16(ahf[mt], blf[nt], acc[mt][nt], 0, 0, 0);
      }
  }
#pragma unroll
  for (int mt = 0; mt < 2; ++mt)
#pragma unroll
    for (int rr = 0; rr < 4; ++rr) {
      int row = wm * 32 + mt * 16 + qd * 4 + rr;
#pragma unroll
      for (int nt = 0; nt < 4; ++nt) {
        int col = nc0 + wn * 64 + nt * 16 + ln;
        atomicAdd(&Cacc[((long)b * K_ + row) * D_ + col], acc[mt][nt][rr]);
      }
    }
}

// --- variant bt: A pre-split [b][64][D_], B = f32 [D][N] transposed in LDS (cost_fea) ---
__global__ __launch_bounds__(256)
void gemm64_bt(const ushort* __restrict__ Ah, const ushort* __restrict__ Al,
               const float* __restrict__ Bf, const float* __restrict__ nrmsq,
               float* __restrict__ cost) {
  __shared__ ushort As[2][64][40];
  __shared__ ushort Bs[2][128][40];
  __shared__ float Ft[32][132];
  const int t = threadIdx.x;
  const int n0 = blockIdx.x * 128;
  const int b = blockIdx.z;
  const float* Fsrc = Bf + (long)b * D_ * N_;
  const bool doA = t < 128;
  const int hA = (t >> 6) & 1, rA = t & 63;
  const ushort* Asrc = (hA ? Al : Ah) + (long)b * K_ * D_ + (long)rA * D_;
  ushort* AsD = &As[hA][rA][0];
  const int dr = t >> 3, cc = (t & 7) * 16;
  const int nl = t & 127, dh = t >> 7;
  const int w = t >> 6, ln = t & 15, qd = (t & 63) >> 4;
  const int wm = w >> 1, wn = w & 1;

  fx4 acc[2][4];
#pragma unroll
  for (int i = 0; i < 2; ++i)
#pragma unroll
    for (int j = 0; j < 4; ++j) acc[i][j] = (fx4)0.f;

  for (int k0 = 0; k0 < D_; k0 += 32) {
    float4 f0 = *(const float4*)(Fsrc + (long)(k0 + dr) * N_ + n0 + cc);
    float4 f1 = *(const float4*)(Fsrc + (long)(k0 + dr) * N_ + n0 + cc + 4);
    float4 f2 = *(const float4*)(Fsrc + (long)(k0 + dr) * N_ + n0 + cc + 8);
    float4 f3 = *(const float4*)(Fsrc + (long)(k0 + dr) * N_ + n0 + cc + 12);
    uint4 a0, a1, a2, a3;
    if (doA) {
      a0 = *(const uint4*)(Asrc + k0);
      a1 = *(const uint4*)(Asrc + k0 + 8);
      a2 = *(const uint4*)(Asrc + k0 + 16);
      a3 = *(const uint4*)(Asrc + k0 + 24);
    }
    __syncthreads();
    *(float4*)&Ft[dr][cc] = f0;
    *(float4*)&Ft[dr][cc + 4] = f1;
    *(float4*)&Ft[dr][cc + 8] = f2;
    *(float4*)&Ft[dr][cc + 12] = f3;
    if (doA) {
      *(uint4*)(AsD + 0) = a0;
      *(uint4*)(AsD + 8) = a1;
      *(uint4*)(AsD + 16) = a2;
      *(uint4*)(AsD + 24) = a3;
    }
    __syncthreads();
    float fv[16];
#pragma unroll
    for (int j = 0; j < 16; ++j) fv[j] = Ft[dh * 16 + j][nl];
    sx8 hv0, hv1, lv0, lv1;
#pragma unroll
    for (int j = 0; j < 8; ++j) {
      ushort h = f2bf(fv[j]);
      hv0[j] = (short)h;
      lv0[j] = (short)f2bf(fv[j] - bf2f(h));
    }
#pragma unroll
    for (int j = 0; j < 8; ++j) {
      ushort h = f2bf(fv[8 + j]);
      hv1[j] = (short)h;
      lv1[j] = (short)f2bf(fv[8 + j] - bf2f(h));
    }
    *(sx8*)&Bs[0][nl][dh * 16] = hv0;
    *(sx8*)&Bs[0][nl][dh * 16 + 8] = hv1;
    *(sx8*)&Bs[1][nl][dh * 16] = lv0;
    *(sx8*)&Bs[1][nl][dh * 16 + 8] = lv1;
    __syncthreads();
    sx8 ahf[2], alf[2], bhf[4], blf[4];
#pragma unroll
    for (int mt = 0; mt < 2; ++mt) {
      ahf[mt] = *(const sx8*)&As[0][wm * 32 + mt * 16 + ln][qd * 8];
      alf[mt] = *(const sx8*)&As[1][wm * 32 + mt * 16 + ln][qd * 8];
    }
#pragma unroll
    for (int nt = 0; nt < 4; ++nt) {
      bhf[nt] = *(const sx8*)&Bs[0][wn * 64 + nt * 16 + ln][qd * 8];
      blf[nt] = *(const sx8*)&Bs[1][wn * 64 + nt * 16 + ln][qd * 8];
    }
#pragma unroll
    for (int mt = 0; mt < 2; ++mt)
#pragma unroll
      for (int nt = 0; nt < 4; ++nt) {
        acc[mt][nt] = __builtin_amdgcn_mfma_f32_16x16x32_bf16(ahf[mt], bhf[nt], acc[mt][nt], 0, 0, 0);
        acc[mt][nt] = __builtin_amdgcn_mfma_f32_16x16x32_bf16(alf[mt], bhf[nt], acc[mt][nt], 0, 0, 0);
        acc[mt][nt] = __builtin_amdgcn_mfma_f32_16x16x32_bf16(ahf[mt], blf[nt], acc[mt][nt], 0, 0, 0);
      }
  }
#pragma unroll
  for (int nt = 0; nt < 4; ++nt) {
    int col = n0 + wn * 64 + nt * 16 + ln;
    float q = nrmsq[b * N_ + col];
    float iv = 1.f / fmaxf(sqrtf(q), 1e-12f);
#pragma unroll
    for (int mt = 0; mt < 2; ++mt)
#pragma unroll
      for (int rr = 0; rr < 4; ++rr) {
        int row = wm * 32 + mt * 16 + qd * 4 + rr;
        cost[((long)b * K_ + row) * N_ + col] = 2.f - 2.f * acc[mt][nt][rr] * iv;
      }
  }
}

// ---------------- softmax: score f32/bf16, logp [b][n][K] ----------------
__global__ __launch_bounds__(256)
void softmax_nk(const float* __restrict__ ls, float* __restrict__ scoreKN,
                ushort* __restrict__ sch, ushort* __restrict__ scl,
                float* __restrict__ logpNK, float* __restrict__ pi_raw) {
  __shared__ float L[64][65];
  __shared__ float ploc[64];
  int tid = threadIdx.x;
  if (tid < 64) ploc[tid] = 0.f;
  __syncthreads();
  int bi = blockIdx.x >> 4;
  int nb = (blockIdx.x & 15) * 256;
  int n = nb + tid;
  const float* x = ls + ((long)bi * K_) * N_ + n;
  float xv[64];
#pragma unroll
  for (int k = 0; k < 64; ++k) xv[k] = x[(long)k * N_];
  float mx = -1e30f;
#pragma unroll
  for (int k = 0; k < 64; ++k) mx = fmaxf(mx, xv[k]);
  float s = 0.f;
#pragma unroll
  for (int k = 0; k < 64; ++k) s += __expf(xv[k] - mx);
  float lg = __logf(s);
  float inv = 1.f / s;
#pragma unroll
  for (int k = 0; k < 64; ++k) {
    float sc = __expf(xv[k] - mx) * inv;
    long o = ((long)bi * K_ + k) * N_ + n;
    scoreKN[o] = sc;
    ushort h = f2bf(sc);
    sch[o] = h;
    scl[o] = f2bf(sc - bf2f(h));
    atomicAdd(&ploc[k], sc);
  }
  __syncthreads();
  if (tid < 64) atomicAdd(&pi_raw[bi * 64 + tid], ploc[tid]);
  int myw = tid >> 6, nl = tid & 63;
  int row = tid >> 2, ch = (tid & 3) * 16;
  for (int p = 0; p < 4; ++p) {
    __syncthreads();
    if (myw == p) {
#pragma unroll
      for (int k = 0; k < 64; ++k) L[nl][k] = xv[k] - mx - lg;
    }
    __syncthreads();
    float o0[16];
#pragma unroll
    for (int j = 0; j < 16; ++j) o0[j] = L[row][ch + j];
    float* dst = logpNK + ((long)bi * N_ + nb + p * 64 + row) * 64 + ch;
    *(float4*)(dst + 0) = make_float4(o0[0], o0[1], o0[2], o0[3]);
    *(float4*)(dst + 4) = make_float4(o0[4], o0[5], o0[6], o0[7]);
    *(float4*)(dst + 8) = make_float4(o0[8], o0[9], o0[10], o0[11]);
    *(float4*)(dst + 12) = make_float4(o0[12], o0[13], o0[14], o0[15]);
  }
}

// ---------------- mu_xyz ----------------
__global__ __launch_bounds__(64)
void mu_xyz_k(const float* __restrict__ scoreKN, const float* __restrict__ xyz,
              const float* __restrict__ pi_raw, float* __restrict__ mu,
              float* __restrict__ yn) {
  int k = blockIdx.x, b = blockIdx.y, t = threadIdx.x;
  const float* st = scoreKN + ((long)b * K_ + k) * N_;
  const float* xp = xyz + (long)b * 3 * N_;
  float a0 = 0, a1 = 0, a2 = 0;
  for (int n = t; n < N_; n += 64) {
    float s = st[n];
    a0 += s * xp[n];
    a1 += s * xp[N_ + n];
    a2 += s * xp[2 * N_ + n];
  }
  for (int off = 32; off > 0; off >>= 1) {
    a0 += __shfl_down(a0, off);
    a1 += __shfl_down(a1, off);
    a2 += __shfl_down(a2, off);
  }
  if (t == 0) {
    float p = fmaxf(pi_raw[b * K_ + k], 1e-4f);
    float m0 = a0 / p, m1 = a1 / p, m2 = a2 / p;
    mu[((long)b * 3 + 0) * K_ + k] = m0;
    mu[((long)b * 3 + 1) * K_ + k] = m1;
    mu[((long)b * 3 + 2) * K_ + k] = m2;
    yn[b * K_ + k] = m0 * m0 + m1 * m1 + m2 * m2;
  }
}

// ---------------- regularizers ----------------
__global__ __launch_bounds__(256)
void reg_xyz_k(const float* __restrict__ mu, float* __restrict__ out) {
  __shared__ float red[256];
  int b = blockIdx.x, tid = threadIdx.x;
  float acc = 0.f;
  for (int e = tid; e < 4096; e += 256) {
    int m = e >> 6, n2 = e & 63;
    float g = 0.f;
    for (int d = 0; d < 3; ++d)
      g += mu[((long)b * 3 + d) * K_ + m] * mu[((long)b * 3 + d) * K_ + n2];
    acc += fabsf(g - (m == n2 ? 1.f : 0.f));
  }
  float tot = block_reduce_sum256(acc, red);
  if (tid == 0) atomicAdd(out, tot * (1e-7f / 32768.f));
}

__global__ __launch_bounds__(256)
void reg_fea_k(const float* __restrict__ nT, float* __restrict__ out) {
  __shared__ float pm[1024];
  __shared__ float red[256];
  int m = blockIdx.x, b = blockIdx.y, tid = threadIdx.x;
  const float* base = nT + (long)b * K_ * D_;
  *(float4*)&pm[tid * 4] = *(const float4*)(base + (long)m * D_ + tid * 4);
  __syncthreads();
  int n2 = tid >> 2, q = tid & 3;
  const float* pn = base + (long)n2 * D_ + q * 256;
  const float* pml = &pm[q * 256];
  float g = 0.f;
#pragma unroll 8
  for (int d = 0; d < 256; d += 4) {
    float4 v = *(const float4*)(pn + d);
    g += v.x * pml[d] + v.y * pml[d + 1] + v.z * pml[d + 2] + v.w * pml[d + 3];
  }
  g += __shfl_down(g, 2);
  g += __shfl_down(g, 1);
  float acc = (q == 0) ? fabsf(g - (m == n2 ? 1.f : 0.f)) : 0.f;
  float tot = block_reduce_sum256(acc, red);
  if (tid == 0) atomicAdd(out, tot * (1e-4f / 32768.f));
}

// ---------------- mu_fea finalize ----------------
__global__ __launch_bounds__(256)
void mu_finalize(const float* __restrict__ muT_raw, const float* __restrict__ pi_raw,
                 float* __restrict__ n_muT, ushort* __restrict__ nmu_h,
                 ushort* __restrict__ nmu_l) {
  __shared__ float red[256];
  int k = blockIdx.x, b = blockIdx.y, tid = threadIdx.x;
  float p = fmaxf(pi_raw[b * K_ + k], 1e-4f);
  const float* src = muT_raw + ((long)b * K_ + k) * D_;
  float ss = 0.f;
  for (int d = tid; d < D_; d += 256) {
    float v = src[d] / p;
    ss += v * v;
  }
  float tot = block_reduce_sum256(ss, red);
  float inv = 1.f / fmaxf(sqrtf(tot), 1e-12f);
  long o = ((long)b * K_ + k) * D_;
  for (int d = tid; d < D_; d += 256) {
    float v = src[d] / p * inv;
    n_muT[o + d] = v;
    ushort h = f2bf(v);
    nmu_h[o + d] = h;
    nmu_l[o + d] = f2bf(v - bf2f(h));
  }
}

// ---------------- cooperative Sinkhorn v4: flag-based arrival ----------------
__global__ __launch_bounds__(256, 1)
void sinkhorn_coop(const float* __restrict__ cost_f, const float* __restrict__ xyz,
                   const float* __restrict__ mu, const float* __restrict__ yn,
                   const float* __restrict__ logpNK, float* __restrict__ out,
                   unsigned long long* __restrict__ partMS,
                   unsigned int* __restrict__ seq) {
  __shared__ float tile[4][64][68];
  __shared__ float vsh[64];
  __shared__ float wm[4][64];
  __shared__ float wsum[4][64];
  __shared__ float red[256];
  __shared__ float mub[4][64];
  const int tid = threadIdx.x;
  const int g = blockIdx.x & 15;
  const int s = blockIdx.x >> 4;
  const int w = tid >> 6, lane = tid & 63;
  const int i = s * 256 + tid;
  const int b = g & 7;
  const float eps = 1e-3f, ti = 1000.0f;
  const float lgp = -8.317766166719343f;
  const float lgq = -4.1588830833596715f;

  float c[64];
  if (g < 8) {
    if (tid < 64) {
      mub[0][tid] = mu[(b * 3 + 0) * K_ + tid];
      mub[1][tid] = mu[(b * 3 + 1) * K_ + tid];
      mub[2][tid] = mu[(b * 3 + 2) * K_ + tid];
      mub[3][tid] = yn[b * K_ + tid];
      vsh[tid] = 0.f;
    }
    __syncthreads();
    float x0 = xyz[((long)b * 3 + 0) * N_ + i];
    float x1 = xyz[((long)b * 3 + 1) * N_ + i];
    float x2 = xyz[((long)b * 3 + 2) * N_ + i];
    float xn = x0 * x0 + x1 * x1 + x2 * x2;
#pragma unroll
    for (int j = 0; j < 64; ++j)
      c[j] = xn + mub[3][j] - 2.f * (x0 * mub[0][j] + x1 * mub[1][j] + x2 * mub[2][j]);
  } else {
    const float* C = cost_f + (long)b * K_ * N_;
#pragma unroll
    for (int j = 0; j < 64; ++j) c[j] = C[(long)j * N_ + i];
    if (tid < 64) vsh[tid] = 0.f;
    __syncthreads();
  }
  float u = 0.f;

  for (int it = 0; it < 25; ++it) {
    float tj[64];
#pragma unroll
    for (int j = 0; j < 64; ++j) tj[j] = vsh[j] - c[j];
    float dm = -1e30f;
#pragma unroll
    for (int j = 0; j < 64; ++j) dm = fmaxf(dm, tj[j]);
    float ssum = 0.f;
#pragma unroll
    for (int j = 0; j < 64; ++j) ssum += __expf((tj[j] - dm) * ti);
    u = eps * (lgp - ((u + dm) * ti + __logf(ssum))) + u;
#pragma unroll
    for (int j4 = 0; j4 < 16; ++j4) {
      float4 v4;
      v4.x = (u + tj[j4 * 4 + 0]) * ti;
      v4.y = (u + tj[j4 * 4 + 1]) * ti;
      v4.z = (u + tj[j4 * 4 + 2]) * ti;
      v4.w = (u + tj[j4 * 4 + 3]) * ti;
      *(float4*)&tile[w][lane][j4 * 4] = v4;
    }
    __syncthreads();
    float M = -1e30f, S = 0.f;
#pragma unroll
    for (int r = 0; r < 64; ++r) {
      float a = tile[w][r][lane];
      M = fmaxf(M, a);
      S += __expf(a - lgp);
    }
    wm[w][lane] = M;
    wsum[w][lane] = S;
    __syncthreads();
    int buf = it & 1;
    if (tid < 64) {
      float Mb = fmaxf(fmaxf(wm[0][tid], wm[1][tid]), fmaxf(wm[2][tid], wm[3][tid]));
      float Sb = wsum[0][tid] + wsum[1][tid] + wsum[2][tid] + wsum[3][tid];
      unsigned long long pk =
          ((unsigned long long)__float_as_uint(Sb) << 32) | (unsigned long long)__float_as_uint(Mb);
      long idx = (((long)buf * 16 + g) * 16 + s) * 64 + tid;
      __hip_atomic_store(&partMS[idx], pk, __ATOMIC_RELAXED, __HIP_MEMORY_SCOPE_AGENT);
    }
    __syncthreads();
    unsigned target = (unsigned)(it + 1);
    if (tid == 0)
      __hip_atomic_store(&seq[((long)g * 16 + s) * 32], target, __ATOMIC_RELEASE,
                         __HIP_MEMORY_SCOPE_AGENT);
    if (tid < 16) {
      while (__hip_atomic_load(&seq[((long)g * 16 + tid) * 32], __ATOMIC_ACQUIRE,
                               __HIP_MEMORY_SCOPE_AGENT) < target)
        __builtin_amdgcn_s_sleep(1);
    }
    __syncthreads();
    if (tid < 64) {
      long base = (((long)buf * 16 + g) * 16) * 64 + tid;
      float M2 = -1e30f, S2 = 0.f;
#pragma unroll
      for (int p = 0; p < 16; ++p) {
        unsigned long long v =
            __hip_atomic_load(&partMS[base + (long)p * 64], __ATOMIC_RELAXED, __HIP_MEMORY_SCOPE_AGENT);
        M2 = fmaxf(M2, __uint_as_float((unsigned)v));
        S2 += __uint_as_float((unsigned)(v >> 32));
      }
      float lsec = fmaxf(M2, lgp + __logf(S2));
      vsh[tid] = eps * (lgq - lsec) + vsh[tid];
    }
    __syncthreads();
  }

  const float* lp = logpNK + ((long)b * N_ + i) * 64;
  float part = 0.f;
#pragma unroll
  for (int j = 0; j < 64; ++j)
    part += __expf((u + vsh[j] - c[j]) * ti) * lp[j];
  red[tid] = part;
  __syncthreads();
  for (int st2 = 128; st2 > 0; st2 >>= 1) {
    if (tid < st2) red[tid] += red[tid + st2];
    __syncthreads();
  }
  if (tid == 0) atomicAdd(out, -red[0] / (float)B_);
}

// ---------------- launch ----------------
extern "C" void kernel_launch(void* const* d_in, const int* in_sizes, int n_in,
                              void* d_out, int out_size, void* d_ws, size_t ws_size,
                              hipStream_t stream) {
  const float* feature = (const float*)d_in[0];
  const float* xyz = (const float*)d_in[1];
  const float* w1 = (const float*)d_in[2];
  const float* b1 = (const float*)d_in[3];
  const float* g1 = (const float*)d_in[4];
  const float* be1 = (const float*)d_in[5];
  const float* w2 = (const float*)d_in[6];
  const float* b2 = (const float*)d_in[7];
  const float* g2 = (const float*)d_in[8];
  const float* be2 = (const float*)d_in[9];
  const float* w3 = (const float*)d_in[10];
  const float* b3 = (const float*)d_in[11];
  float* out = (float*)d_out;
  float* ws = (float*)d_ws;

  const long RSZ = 16777216L;
  float* regA = ws;       // h1raw, later phase-3 arrays
  float* regB1 = ws + RSZ;  // h2raw
  float* sm = ws + 3 * RSZ;

  float* h1raw = regA;
  float* h2raw = regB1;
  const long sz = (long)B_ * N_ * K_;
  float* log_score = regA;                 // reuses h1raw (dead after conv2)
  float* score_KN = regA + sz;
  float* logpNK = regA + 2 * sz;
  float* cost_f = regA + 3 * sz;
  ushort* sc_h = (ushort*)(regA + 4 * sz);
  ushort* sc_l = (ushort*)(regA + 4 * sz) + sz;

  ushort* Wh1 = (ushort*)sm; sm += 262144;
  ushort* Wl1 = (ushort*)sm; sm += 262144;
  ushort* Wh2 = (ushort*)sm; sm += 131072;
  ushort* Wl2 = (ushort*)sm; sm += 131072;
  ushort* Wh3 = (ushort*)sm; sm += 16384;
  ushort* Wl3 = (ushort*)sm; sm += 16384;
  float* muT_raw = sm; sm += (long)B_ * K_ * D_;
  float* n_muT = sm;   sm += (long)B_ * K_ * D_;
  ushort* nmu_h = (ushort*)sm; sm += 262144;
  ushort* nmu_l = (ushort*)sm; sm += 262144;
  unsigned long long* partMS = (unsigned long long*)sm; sm += 2 * 16 * 16 * 64 * 2;
  unsigned int* seq = (unsigned int*)sm; sm += 16 * 16 * 32;
  float* nrmsq = sm; sm += (long)B_ * N_;
  float* mu_x = sm;   sm += 2048;
  float* yn = sm;     sm += 512;
  float* pi_raw = sm; sm += 512;
  float* rs1 = sm; sm += 512;
  float* rss1 = sm; sm += 512;
  float* rs2 = sm; sm += 512;
  float* rss2 = sm; sm += 512;
  float* sc1 = sm; sm += 512;
  float* sh1 = sm; sm += 512;
  float* sc2 = sm; sm += 512;
  float* sh2 = sm; sm += 512;

  hipMemsetAsync(d_out, 0, sizeof(float) * out_size, stream);
  hipMemsetAsync(pi_raw, 0, 512 * sizeof(float), stream);
  hipMemsetAsync(seq, 0, 16 * 16 * 32 * sizeof(unsigned int), stream);
  hipMemsetAsync(muT_raw, 0, (long)B_ * K_ * D_ * sizeof(float), stream);
  hipMemsetAsync(nrmsq, 0, (long)B_ * N_ * sizeof(float), stream);
  hipMemsetAsync(rs1, 0, 4 * 512 * sizeof(float), stream);

  split_w3<<<3200, 256, 0, stream>>>(w1, w2, w3, Wh1, Wl1, Wh2, Wl2, Wh3, Wl3);
  // conv1: B = feature f32 (no BN), stats -> rs1/rss1, nrmsq fused
  {
    dim3 g(N_ / 128, H_ / 128, B_);
    conv_bt128<<<g, 256, 0, stream>>>(Wh1, Wl1, feature, nullptr, nullptr, h1raw,
                                      b1, rs1, rss1, nrmsq, D_, (long)D_ * N_,
                                      (long)H_ * N_);
  }
  bn_fin<<<2, 256, 0, stream>>>(rs1, rss1, g1, be1, sc1, sh1);
  // conv2: B = h1raw with BN1+ReLU fused, stats -> rs2/rss2
  {
    dim3 g(N_ / 128, H_ / 128, B_);
    conv_bt128<<<g, 256, 0, stream>>>(Wh2, Wl2, h1raw, sc1, sh1, h2raw, b2, rs2,
                                      rss2, nullptr, H_, (long)H_ * N_,
                                      (long)H_ * N_);
  }
  bn_fin<<<2, 256, 0, stream>>>(rs2, rss2, g2, be2, sc2, sh2);
  // conv3: B = h2raw with BN2+ReLU fused
  {
    dim3 g(N_ / 128, 1, B_);
    conv64_bn<<<g, 256, 0, stream>>>(Wh3, Wl3, h2raw, sc2, sh2, log_score, b3,
                                     H_, (long)H_ * N_, (long)K_ * N_);
  }
  softmax_nk<<<B_ * N_ / 256, 256, 0, stream>>>(log_score, score_KN, sc_h, sc_l,
                                                logpNK, pi_raw);
  {
    dim3 g(K_, B_);
    mu_xyz_k<<<g, 64, 0, stream>>>(score_KN, xyz, pi_raw, mu_x, yn);
  }
  reg_xyz_k<<<B_, 256, 0, stream>>>(mu_x, out);
  // mu_fea
  {
    dim3 g(D_ / 128, 4, B_);
    gemm64_bf<<<g, 256, 0, stream>>>(sc_h, sc_l, feature, muT_raw);
  }
  {
    dim3 g(K_, B_);
    mu_finalize<<<g, 256, 0, stream>>>(muT_raw, pi_raw, n_muT, nmu_h, nmu_l);
  }
  {
    dim3 g(K_, B_);
    reg_fea_k<<<g, 256, 0, stream>>>(n_muT, out);
  }
  // cost_fea
  {
    dim3 g(N_ / 128, 1, B_);
    gemm64_bt<<<g, 256, 0, stream>>>(nmu_h, nmu_l, feature, nrmsq, cost_f);
  }
  // cooperative Sinkhorn + fused loss
  {
    void* kargs[] = {(void*)&cost_f, (void*)&xyz, (void*)&mu_x, (void*)&yn,
                     (void*)&logpNK, (void*)&out, (void*)&partMS, (void*)&seq};
    hipLaunchCooperativeKernel((const void*)sinkhorn_coop, dim3(256), dim3(256),
                               kargs, 0, stream);
  }
}

// Round 10
// 1050.044 us; speedup vs baseline: 1.1319x; 1.0245x over previous
//
#include <hip/hip_runtime.h>
#include <math.h>

#define B_ 8
#define D_ 1024
#define N_ 4096
#define K_ 64
#define H_ 512

typedef short sx8 __attribute__((ext_vector_type(8)));
typedef float fx4 __attribute__((ext_vector_type(4)));

// ---------------- helpers ----------------
__device__ __forceinline__ float block_reduce_sum256(float v, float* sm) {
  int tid = threadIdx.x;
  sm[tid] = v;
  __syncthreads();
  for (int s = 128; s > 0; s >>= 1) {
    if (tid < s) sm[tid] += sm[tid + s];
    __syncthreads();
  }
  float r = sm[0];
  __syncthreads();
  return r;
}

__device__ __forceinline__ float bf2f(ushort h) {
  return __uint_as_float(((unsigned)h) << 16);
}
// truncation split: hi = trunc16(f) (error goes exactly into lo), lo = trunc16(f-hi)
// 4 VALU/value vs ~11 for RNE; residual ~2^-16 relative.
__device__ __forceinline__ void split2(float f, ushort& h, ushort& l) {
  unsigned u = __float_as_uint(f);
  float hf = __uint_as_float(u & 0xffff0000u);
  h = (ushort)(u >> 16);
  l = (ushort)(__float_as_uint(f - hf) >> 16);
}

// ---------------- fused weight split ----------------
__global__ __launch_bounds__(256)
void split_w3(const float* __restrict__ W1, const float* __restrict__ W2,
              const float* __restrict__ W3, ushort* __restrict__ Wh1,
              ushort* __restrict__ Wl1, ushort* __restrict__ Wh2,
              ushort* __restrict__ Wl2, ushort* __restrict__ Wh3,
              ushort* __restrict__ Wl3) {
  int i = blockIdx.x * 256 + threadIdx.x;
  const float* W;
  ushort *Wh, *Wl;
  int o;
  if (i < 524288) { W = W1; Wh = Wh1; Wl = Wl1; o = i; }
  else if (i < 786432) { W = W2; Wh = Wh2; Wl = Wl2; o = i - 524288; }
  else { W = W3; Wh = Wh3; Wl = Wl3; o = i - 786432; }
  ushort h, l;
  split2(W[o], h, l);
  Wh[o] = h;
  Wl[o] = l;
}

// ---------------- conv_bt128: M=128/block split-bf16 MFMA GEMM ----------------
__global__ __launch_bounds__(256)
void conv_bt128(const ushort* __restrict__ Ah, const ushort* __restrict__ Al,
                const float* __restrict__ Bf, const float* __restrict__ scale,
                const float* __restrict__ shift, float* __restrict__ C,
                const float* __restrict__ bias, float* __restrict__ rs,
                float* __restrict__ rss, float* __restrict__ nrm,
                int Kd, long sB, long sC) {
  __shared__ ushort As[2][128][40];
  __shared__ ushort Bs[2][128][40];
  __shared__ float Ft[32][132];
  __shared__ float scb[32], shb[32];
  __shared__ float rs_l[128], rss_l[128];
  const int t = threadIdx.x;
  const int n0 = blockIdx.x * 128;
  const int m0 = blockIdx.y * 128;
  const int b = blockIdx.z;
  const float* Fsrc = Bf + (long)b * sB;
  float* Cp = C + (long)b * sC;
  const int half = t >> 7, rA = t & 127;
  const ushort* Asrc = (half ? Al : Ah) + (long)(m0 + rA) * Kd;
  ushort* AsD = &As[half][rA][0];
  const int dr = t >> 3, cc = (t & 7) * 16;
  const int nl = t & 127, dh = t >> 7;
  const int w = t >> 6, ln = t & 15, qd = (t & 63) >> 4;
  const int wm = w >> 1, wn = w & 1;
  if (t < 128) { rs_l[t] = 0.f; rss_l[t] = 0.f; }
  float nsq = 0.f;

  fx4 acc[4][4];
#pragma unroll
  for (int i = 0; i < 4; ++i)
#pragma unroll
    for (int j = 0; j < 4; ++j) acc[i][j] = (fx4)0.f;

  for (int k0 = 0; k0 < Kd; k0 += 32) {
    float4 f0 = *(const float4*)(Fsrc + (long)(k0 + dr) * N_ + n0 + cc);
    float4 f1 = *(const float4*)(Fsrc + (long)(k0 + dr) * N_ + n0 + cc + 4);
    float4 f2 = *(const float4*)(Fsrc + (long)(k0 + dr) * N_ + n0 + cc + 8);
    float4 f3 = *(const float4*)(Fsrc + (long)(k0 + dr) * N_ + n0 + cc + 12);
    uint4 a0 = *(const uint4*)(Asrc + k0);
    uint4 a1 = *(const uint4*)(Asrc + k0 + 8);
    uint4 a2 = *(const uint4*)(Asrc + k0 + 16);
    uint4 a3 = *(const uint4*)(Asrc + k0 + 24);
    __syncthreads();
    *(float4*)&Ft[dr][cc] = f0;
    *(float4*)&Ft[dr][cc + 4] = f1;
    *(float4*)&Ft[dr][cc + 8] = f2;
    *(float4*)&Ft[dr][cc + 12] = f3;
    *(uint4*)(AsD + 0) = a0;
    *(uint4*)(AsD + 8) = a1;
    *(uint4*)(AsD + 16) = a2;
    *(uint4*)(AsD + 24) = a3;
    if (t < 32) {
      scb[t] = scale ? scale[k0 + t] : 1.f;
      shb[t] = scale ? shift[k0 + t] : 0.f;
    }
    __syncthreads();
    sx8 hv0, hv1, lv0, lv1;
#pragma unroll
    for (int j = 0; j < 8; ++j) {
      float v = Ft[dh * 16 + j][nl];
      if (scale) v = fmaxf(v * scb[dh * 16 + j] + shb[dh * 16 + j], 0.f);
      nsq += v * v;
      ushort h, l;
      split2(v, h, l);
      hv0[j] = (short)h;
      lv0[j] = (short)l;
    }
#pragma unroll
    for (int j = 0; j < 8; ++j) {
      float v = Ft[dh * 16 + 8 + j][nl];
      if (scale) v = fmaxf(v * scb[dh * 16 + 8 + j] + shb[dh * 16 + 8 + j], 0.f);
      nsq += v * v;
      ushort h, l;
      split2(v, h, l);
      hv1[j] = (short)h;
      lv1[j] = (short)l;
    }
    *(sx8*)&Bs[0][nl][dh * 16] = hv0;
    *(sx8*)&Bs[0][nl][dh * 16 + 8] = hv1;
    *(sx8*)&Bs[1][nl][dh * 16] = lv0;
    *(sx8*)&Bs[1][nl][dh * 16 + 8] = lv1;
    __syncthreads();
    sx8 ahf[4], alf[4], bhf[4], blf[4];
#pragma unroll
    for (int mt = 0; mt < 4; ++mt) {
      ahf[mt] = *(const sx8*)&As[0][wm * 64 + mt * 16 + ln][qd * 8];
      alf[mt] = *(const sx8*)&As[1][wm * 64 + mt * 16 + ln][qd * 8];
    }
#pragma unroll
    for (int nt = 0; nt < 4; ++nt) {
      bhf[nt] = *(const sx8*)&Bs[0][wn * 64 + nt * 16 + ln][qd * 8];
      blf[nt] = *(const sx8*)&Bs[1][wn * 64 + nt * 16 + ln][qd * 8];
    }
#pragma unroll
    for (int mt = 0; mt < 4; ++mt)
#pragma unroll
      for (int nt = 0; nt < 4; ++nt) {
        acc[mt][nt] = __builtin_amdgcn_mfma_f32_16x16x32_bf16(ahf[mt], bhf[nt], acc[mt][nt], 0, 0, 0);
        acc[mt][nt] = __builtin_amdgcn_mfma_f32_16x16x32_bf16(alf[mt], bhf[nt], acc[mt][nt], 0, 0, 0);
        acc[mt][nt] = __builtin_amdgcn_mfma_f32_16x16x32_bf16(ahf[mt], blf[nt], acc[mt][nt], 0, 0, 0);
      }
  }
#pragma unroll
  for (int mt = 0; mt < 4; ++mt) {
#pragma unroll
    for (int rr = 0; rr < 4; ++rr) {
      int rloc = wm * 64 + mt * 16 + qd * 4 + rr;
      int row = m0 + rloc;
      float bb = bias[row];
      float s1 = 0.f, s2 = 0.f;
#pragma unroll
      for (int nt = 0; nt < 4; ++nt) {
        int col = n0 + wn * 64 + nt * 16 + ln;
        float y = acc[mt][nt][rr] + bb;
        Cp[(long)row * N_ + col] = y;
        s1 += y;
        s2 += y * y;
      }
      if (rs) {
#pragma unroll
        for (int m = 1; m < 16; m <<= 1) {
          s1 += __shfl_xor(s1, m);
          s2 += __shfl_xor(s2, m);
        }
        if (ln == 0) {
          atomicAdd(&rs_l[rloc], s1);
          atomicAdd(&rss_l[rloc], s2);
        }
      }
    }
  }
  if (nrm && blockIdx.y == 0)
    atomicAdd(&nrm[(long)b * N_ + n0 + nl], nsq);
  if (rs) {
    __syncthreads();
    if (t < 128) {
      atomicAdd(&rs[m0 + t], rs_l[t]);
      atomicAdd(&rss[m0 + t], rss_l[t]);
    }
  }
}

// ---------------- bn_fin ----------------
__global__ void bn_fin(const float* __restrict__ rs, const float* __restrict__ rss,
                       const float* __restrict__ g, const float* __restrict__ be,
                       float* __restrict__ sc, float* __restrict__ sh) {
  int c = blockIdx.x * 256 + threadIdx.x;
  if (c < H_) {
    float inv = 1.f / (float)(B_ * N_);
    float m = rs[c] * inv;
    float var = rss[c] * inv - m * m;
    float s = g[c] * rsqrtf(var + 1e-5f);
    sc[c] = s;
    sh[c] = be[c] - m * s;
  }
}

// ---------------- conv64_bn: conv3 (M=64, BN2-fused B staging) ----------------
__global__ __launch_bounds__(256)
void conv64_bn(const ushort* __restrict__ Ah, const ushort* __restrict__ Al,
               const float* __restrict__ Bf, const float* __restrict__ scale,
               const float* __restrict__ shift, float* __restrict__ C,
               const float* __restrict__ bias, int Kd, long sB, long sC) {
  __shared__ ushort As[2][64][40];
  __shared__ ushort Bs[2][128][40];
  __shared__ float Ft[32][132];
  __shared__ float scb[32], shb[32];
  const int t = threadIdx.x;
  const int n0 = blockIdx.x * 128;
  const int b = blockIdx.z;
  const float* Fsrc = Bf + (long)b * sB;
  float* Cp = C + (long)b * sC;
  const bool doA = t < 128;
  const int hA = (t >> 6) & 1, rA = t & 63;
  const ushort* Asrc = (hA ? Al : Ah) + (long)rA * Kd;
  ushort* AsD = &As[hA][rA][0];
  const int dr = t >> 3, cc = (t & 7) * 16;
  const int nl = t & 127, dh = t >> 7;
  const int w = t >> 6, ln = t & 15, qd = (t & 63) >> 4;
  const int wm = w >> 1, wn = w & 1;

  fx4 acc[2][4];
#pragma unroll
  for (int i = 0; i < 2; ++i)
#pragma unroll
    for (int j = 0; j < 4; ++j) acc[i][j] = (fx4)0.f;

  for (int k0 = 0; k0 < Kd; k0 += 32) {
    float4 f0 = *(const float4*)(Fsrc + (long)(k0 + dr) * N_ + n0 + cc);
    float4 f1 = *(const float4*)(Fsrc + (long)(k0 + dr) * N_ + n0 + cc + 4);
    float4 f2 = *(const float4*)(Fsrc + (long)(k0 + dr) * N_ + n0 + cc + 8);
    float4 f3 = *(const float4*)(Fsrc + (long)(k0 + dr) * N_ + n0 + cc + 12);
    uint4 a0, a1, a2, a3;
    if (doA) {
      a0 = *(const uint4*)(Asrc + k0);
      a1 = *(const uint4*)(Asrc + k0 + 8);
      a2 = *(const uint4*)(Asrc + k0 + 16);
      a3 = *(const uint4*)(Asrc + k0 + 24);
    }
    __syncthreads();
    *(float4*)&Ft[dr][cc] = f0;
    *(float4*)&Ft[dr][cc + 4] = f1;
    *(float4*)&Ft[dr][cc + 8] = f2;
    *(float4*)&Ft[dr][cc + 12] = f3;
    if (doA) {
      *(uint4*)(AsD + 0) = a0;
      *(uint4*)(AsD + 8) = a1;
      *(uint4*)(AsD + 16) = a2;
      *(uint4*)(AsD + 24) = a3;
    }
    if (t < 32) {
      scb[t] = scale[k0 + t];
      shb[t] = shift[k0 + t];
    }
    __syncthreads();
    sx8 hv0, hv1, lv0, lv1;
#pragma unroll
    for (int j = 0; j < 8; ++j) {
      float v = Ft[dh * 16 + j][nl];
      v = fmaxf(v * scb[dh * 16 + j] + shb[dh * 16 + j], 0.f);
      ushort h, l;
      split2(v, h, l);
      hv0[j] = (short)h;
      lv0[j] = (short)l;
    }
#pragma unroll
    for (int j = 0; j < 8; ++j) {
      float v = Ft[dh * 16 + 8 + j][nl];
      v = fmaxf(v * scb[dh * 16 + 8 + j] + shb[dh * 16 + 8 + j], 0.f);
      ushort h, l;
      split2(v, h, l);
      hv1[j] = (short)h;
      lv1[j] = (short)l;
    }
    *(sx8*)&Bs[0][nl][dh * 16] = hv0;
    *(sx8*)&Bs[0][nl][dh * 16 + 8] = hv1;
    *(sx8*)&Bs[1][nl][dh * 16] = lv0;
    *(sx8*)&Bs[1][nl][dh * 16 + 8] = lv1;
    __syncthreads();
    sx8 ahf[2], alf[2], bhf[4], blf[4];
#pragma unroll
    for (int mt = 0; mt < 2; ++mt) {
      ahf[mt] = *(const sx8*)&As[0][wm * 32 + mt * 16 + ln][qd * 8];
      alf[mt] = *(const sx8*)&As[1][wm * 32 + mt * 16 + ln][qd * 8];
    }
#pragma unroll
    for (int nt = 0; nt < 4; ++nt) {
      bhf[nt] = *(const sx8*)&Bs[0][wn * 64 + nt * 16 + ln][qd * 8];
      blf[nt] = *(const sx8*)&Bs[1][wn * 64 + nt * 16 + ln][qd * 8];
    }
#pragma unroll
    for (int mt = 0; mt < 2; ++mt)
#pragma unroll
      for (int nt = 0; nt < 4; ++nt) {
        acc[mt][nt] = __builtin_amdgcn_mfma_f32_16x16x32_bf16(ahf[mt], bhf[nt], acc[mt][nt], 0, 0, 0);
        acc[mt][nt] = __builtin_amdgcn_mfma_f32_16x16x32_bf16(alf[mt], bhf[nt], acc[mt][nt], 0, 0, 0);
        acc[mt][nt] = __builtin_amdgcn_mfma_f32_16x16x32_bf16(ahf[mt], blf[nt], acc[mt][nt], 0, 0, 0);
      }
  }
#pragma unroll
  for (int mt = 0; mt < 2; ++mt)
#pragma unroll
    for (int rr = 0; rr < 4; ++rr) {
      int row = wm * 32 + mt * 16 + qd * 4 + rr;
      float bb = bias[row];
#pragma unroll
      for (int nt = 0; nt < 4; ++nt) {
        int col = n0 + wn * 64 + nt * 16 + ln;
        Cp[(long)row * N_ + col] = acc[mt][nt][rr] + bb;
      }
    }
}

// --- variant bf: A pre-split [b][64][N_], B = f32 rows natural along Kd (mu_fea) ---
__global__ __launch_bounds__(256)
void gemm64_bf(const ushort* __restrict__ Ah, const ushort* __restrict__ Al,
               const float* __restrict__ Bf, float* __restrict__ Cacc) {
  __shared__ ushort As[2][64][40];
  __shared__ ushort Bs[2][128][40];
  const int t = threadIdx.x;
  const int nc0 = blockIdx.x * 128;
  const int kBeg = blockIdx.y * 1024;
  const int b = blockIdx.z;
  const int pc = t >> 7, rB = t & 127;
  const float* Bsrc = Bf + (long)b * D_ * N_ + (long)(nc0 + rB) * N_ + kBeg + pc * 16;
  const bool doA = t < 128;
  const int hA = (t >> 6) & 1, rA = t & 63;
  const ushort* Asrc = (hA ? Al : Ah) + (long)b * K_ * N_ + (long)rA * N_ + kBeg;
  ushort* AsD = &As[hA][rA][0];
  const int w = t >> 6, ln = t & 15, qd = (t & 63) >> 4;
  const int wm = w >> 1, wn = w & 1;

  fx4 acc[2][4];
#pragma unroll
  for (int i = 0; i < 2; ++i)
#pragma unroll
    for (int j = 0; j < 4; ++j) acc[i][j] = (fx4)0.f;

  for (int k0 = 0; k0 < 1024; k0 += 32) {
    float4 f0 = *(const float4*)(Bsrc + k0);
    float4 f1 = *(const float4*)(Bsrc + k0 + 4);
    float4 f2 = *(const float4*)(Bsrc + k0 + 8);
    float4 f3 = *(const float4*)(Bsrc + k0 + 12);
    uint4 a0, a1, a2, a3;
    if (doA) {
      a0 = *(const uint4*)(Asrc + k0);
      a1 = *(const uint4*)(Asrc + k0 + 8);
      a2 = *(const uint4*)(Asrc + k0 + 16);
      a3 = *(const uint4*)(Asrc + k0 + 24);
    }
    float fv[16] = {f0.x, f0.y, f0.z, f0.w, f1.x, f1.y, f1.z, f1.w,
                    f2.x, f2.y, f2.z, f2.w, f3.x, f3.y, f3.z, f3.w};
    sx8 hv0, hv1, lv0, lv1;
#pragma unroll
    for (int j = 0; j < 8; ++j) {
      ushort h, l;
      split2(fv[j], h, l);
      hv0[j] = (short)h;
      lv0[j] = (short)l;
    }
#pragma unroll
    for (int j = 0; j < 8; ++j) {
      ushort h, l;
      split2(fv[8 + j], h, l);
      hv1[j] = (short)h;
      lv1[j] = (short)l;
    }
    __syncthreads();
    *(sx8*)&Bs[0][rB][pc * 16] = hv0;
    *(sx8*)&Bs[0][rB][pc * 16 + 8] = hv1;
    *(sx8*)&Bs[1][rB][pc * 16] = lv0;
    *(sx8*)&Bs[1][rB][pc * 16 + 8] = lv1;
    if (doA) {
      *(uint4*)(AsD + 0) = a0;
      *(uint4*)(AsD + 8) = a1;
      *(uint4*)(AsD + 16) = a2;
      *(uint4*)(AsD + 24) = a3;
    }
    __syncthreads();
    sx8 ahf[2], alf[2], bhf[4], blf[4];
#pragma unroll
    for (int mt = 0; mt < 2; ++mt) {
      ahf[mt] = *(const sx8*)&As[0][wm * 32 + mt * 16 + ln][qd * 8];
      alf[mt] = *(const sx8*)&As[1][wm * 32 + mt * 16 + ln][qd * 8];
    }
#pragma unroll
    for (int nt = 0; nt < 4; ++nt) {
      bhf[nt] = *(const sx8*)&Bs[0][wn * 64 + nt * 16 + ln][qd * 8];
      blf[nt] = *(const sx8*)&Bs[1][wn * 64 + nt * 16 + ln][qd * 8];
    }
#pragma unroll
    for (int mt = 0; mt < 2; ++mt)
#pragma unroll
      for (int nt = 0; nt < 4; ++nt) {
        acc[mt][nt] = __builtin_amdgcn_mfma_f32_16x16x32_bf16(ahf[mt], bhf[nt], acc[mt][nt], 0, 0, 0);
        acc[mt][nt] = __builtin_amdgcn_mfma_f32_16x16x32_bf16(alf[mt], bhf[nt], acc[mt][nt], 0, 0, 0);
        acc[mt][nt] = __builtin_amdgcn_mfma_f32_16x16x32_bf16(ahf[mt], blf[nt], acc[mt][nt], 0, 0, 0);
      }
  }
#pragma unroll
  for (int mt = 0; mt < 2; ++mt)
#pragma unroll
    for (int rr = 0; rr < 4; ++rr) {
      int row = wm * 32 + mt * 16 + qd * 4 + rr;
#pragma unroll
      for (int nt = 0; nt < 4; ++nt) {
        int col = nc0 + wn * 64 + nt * 16 + ln;
        atomicAdd(&Cacc[((long)b * K_ + row) * D_ + col], acc[mt][nt][rr]);
      }
    }
}

// --- variant bt: A pre-split [b][64][D_], B = f32 [D][N] transposed in LDS (cost_fea) ---
__global__ __launch_bounds__(256)
void gemm64_bt(const ushort* __restrict__ Ah, const ushort* __restrict__ Al,
               const float* __restrict__ Bf, const float* __restrict__ nrmsq,
               float* __restrict__ cost) {
  __shared__ ushort As[2][64][40];
  __shared__ ushort Bs[2][128][40];
  __shared__ float Ft[32][132];
  const int t = threadIdx.x;
  const int n0 = blockIdx.x * 128;
  const int b = blockIdx.z;
  const float* Fsrc = Bf + (long)b * D_ * N_;
  const bool doA = t < 128;
  const int hA = (t >> 6) & 1, rA = t & 63;
  const ushort* Asrc = (hA ? Al : Ah) + (long)b * K_ * D_ + (long)rA * D_;
  ushort* AsD = &As[hA][rA][0];
  const int dr = t >> 3, cc = (t & 7) * 16;
  const int nl = t & 127, dh = t >> 7;
  const int w = t >> 6, ln = t & 15, qd = (t & 63) >> 4;
  const int wm = w >> 1, wn = w & 1;

  fx4 acc[2][4];
#pragma unroll
  for (int i = 0; i < 2; ++i)
#pragma unroll
    for (int j = 0; j < 4; ++j) acc[i][j] = (fx4)0.f;

  for (int k0 = 0; k0 < D_; k0 += 32) {
    float4 f0 = *(const float4*)(Fsrc + (long)(k0 + dr) * N_ + n0 + cc);
    float4 f1 = *(const float4*)(Fsrc + (long)(k0 + dr) * N_ + n0 + cc + 4);
    float4 f2 = *(const float4*)(Fsrc + (long)(k0 + dr) * N_ + n0 + cc + 8);
    float4 f3 = *(const float4*)(Fsrc + (long)(k0 + dr) * N_ + n0 + cc + 12);
    uint4 a0, a1, a2, a3;
    if (doA) {
      a0 = *(const uint4*)(Asrc + k0);
      a1 = *(const uint4*)(Asrc + k0 + 8);
      a2 = *(const uint4*)(Asrc + k0 + 16);
      a3 = *(const uint4*)(Asrc + k0 + 24);
    }
    __syncthreads();
    *(float4*)&Ft[dr][cc] = f0;
    *(float4*)&Ft[dr][cc + 4] = f1;
    *(float4*)&Ft[dr][cc + 8] = f2;
    *(float4*)&Ft[dr][cc + 12] = f3;
    if (doA) {
      *(uint4*)(AsD + 0) = a0;
      *(uint4*)(AsD + 8) = a1;
      *(uint4*)(AsD + 16) = a2;
      *(uint4*)(AsD + 24) = a3;
    }
    __syncthreads();
    sx8 hv0, hv1, lv0, lv1;
#pragma unroll
    for (int j = 0; j < 8; ++j) {
      ushort h, l;
      split2(Ft[dh * 16 + j][nl], h, l);
      hv0[j] = (short)h;
      lv0[j] = (short)l;
    }
#pragma unroll
    for (int j = 0; j < 8; ++j) {
      ushort h, l;
      split2(Ft[dh * 16 + 8 + j][nl], h, l);
      hv1[j] = (short)h;
      lv1[j] = (short)l;
    }
    *(sx8*)&Bs[0][nl][dh * 16] = hv0;
    *(sx8*)&Bs[0][nl][dh * 16 + 8] = hv1;
    *(sx8*)&Bs[1][nl][dh * 16] = lv0;
    *(sx8*)&Bs[1][nl][dh * 16 + 8] = lv1;
    __syncthreads();
    sx8 ahf[2], alf[2], bhf[4], blf[4];
#pragma unroll
    for (int mt = 0; mt < 2; ++mt) {
      ahf[mt] = *(const sx8*)&As[0][wm * 32 + mt * 16 + ln][qd * 8];
      alf[mt] = *(const sx8*)&As[1][wm * 32 + mt * 16 + ln][qd * 8];
    }
#pragma unroll
    for (int nt = 0; nt < 4; ++nt) {
      bhf[nt] = *(const sx8*)&Bs[0][wn * 64 + nt * 16 + ln][qd * 8];
      blf[nt] = *(const sx8*)&Bs[1][wn * 64 + nt * 16 + ln][qd * 8];
    }
#pragma unroll
    for (int mt = 0; mt < 2; ++mt)
#pragma unroll
      for (int nt = 0; nt < 4; ++nt) {
        acc[mt][nt] = __builtin_amdgcn_mfma_f32_16x16x32_bf16(ahf[mt], bhf[nt], acc[mt][nt], 0, 0, 0);
        acc[mt][nt] = __builtin_amdgcn_mfma_f32_16x16x32_bf16(alf[mt], bhf[nt], acc[mt][nt], 0, 0, 0);
        acc[mt][nt] = __builtin_amdgcn_mfma_f32_16x16x32_bf16(ahf[mt], blf[nt], acc[mt][nt], 0, 0, 0);
      }
  }
#pragma unroll
  for (int nt = 0; nt < 4; ++nt) {
    int col = n0 + wn * 64 + nt * 16 + ln;
    float q = nrmsq[b * N_ + col];
    float iv = 1.f / fmaxf(sqrtf(q), 1e-12f);
#pragma unroll
    for (int mt = 0; mt < 2; ++mt)
#pragma unroll
      for (int rr = 0; rr < 4; ++rr) {
        int row = wm * 32 + mt * 16 + qd * 4 + rr;
        cost[((long)b * K_ + row) * N_ + col] = 2.f - 2.f * acc[mt][nt][rr] * iv;
      }
  }
}

// ---------------- softmax: score bf16 hi/lo only, logp [b][n][K] ----------------
__global__ __launch_bounds__(256)
void softmax_nk(const float* __restrict__ ls, ushort* __restrict__ sch,
                ushort* __restrict__ scl, float* __restrict__ logpNK,
                float* __restrict__ pi_raw) {
  __shared__ float L[64][65];
  __shared__ float ploc[64];
  int tid = threadIdx.x;
  if (tid < 64) ploc[tid] = 0.f;
  __syncthreads();
  int bi = blockIdx.x >> 4;
  int nb = (blockIdx.x & 15) * 256;
  int n = nb + tid;
  const float* x = ls + ((long)bi * K_) * N_ + n;
  float xv[64];
#pragma unroll
  for (int k = 0; k < 64; ++k) xv[k] = x[(long)k * N_];
  float mx = -1e30f;
#pragma unroll
  for (int k = 0; k < 64; ++k) mx = fmaxf(mx, xv[k]);
  float s = 0.f;
#pragma unroll
  for (int k = 0; k < 64; ++k) s += __expf(xv[k] - mx);
  float lg = __logf(s);
  float inv = 1.f / s;
#pragma unroll
  for (int k = 0; k < 64; ++k) {
    float sc = __expf(xv[k] - mx) * inv;
    long o = ((long)bi * K_ + k) * N_ + n;
    ushort h, l;
    split2(sc, h, l);
    sch[o] = h;
    scl[o] = l;
    atomicAdd(&ploc[k], sc);
  }
  __syncthreads();
  if (tid < 64) atomicAdd(&pi_raw[bi * 64 + tid], ploc[tid]);
  int myw = tid >> 6, nl = tid & 63;
  int row = tid >> 2, ch = (tid & 3) * 16;
  for (int p = 0; p < 4; ++p) {
    __syncthreads();
    if (myw == p) {
#pragma unroll
      for (int k = 0; k < 64; ++k) L[nl][k] = xv[k] - mx - lg;
    }
    __syncthreads();
    float o0[16];
#pragma unroll
    for (int j = 0; j < 16; ++j) o0[j] = L[row][ch + j];
    float* dst = logpNK + ((long)bi * N_ + nb + p * 64 + row) * 64 + ch;
    *(float4*)(dst + 0) = make_float4(o0[0], o0[1], o0[2], o0[3]);
    *(float4*)(dst + 4) = make_float4(o0[4], o0[5], o0[6], o0[7]);
    *(float4*)(dst + 8) = make_float4(o0[8], o0[9], o0[10], o0[11]);
    *(float4*)(dst + 12) = make_float4(o0[12], o0[13], o0[14], o0[15]);
  }
}

// ---------------- mu_xyz (reads bf16 hi/lo score) ----------------
__global__ __launch_bounds__(64)
void mu_xyz_k(const ushort* __restrict__ sch, const ushort* __restrict__ scl,
              const float* __restrict__ xyz, const float* __restrict__ pi_raw,
              float* __restrict__ mu, float* __restrict__ yn) {
  int k = blockIdx.x, b = blockIdx.y, t = threadIdx.x;
  const ushort* sh = sch + ((long)b * K_ + k) * N_;
  const ushort* sl = scl + ((long)b * K_ + k) * N_;
  const float* xp = xyz + (long)b * 3 * N_;
  float a0 = 0, a1 = 0, a2 = 0;
  for (int n = t; n < N_; n += 64) {
    float s = bf2f(sh[n]) + bf2f(sl[n]);
    a0 += s * xp[n];
    a1 += s * xp[N_ + n];
    a2 += s * xp[2 * N_ + n];
  }
  for (int off = 32; off > 0; off >>= 1) {
    a0 += __shfl_down(a0, off);
    a1 += __shfl_down(a1, off);
    a2 += __shfl_down(a2, off);
  }
  if (t == 0) {
    float p = fmaxf(pi_raw[b * K_ + k], 1e-4f);
    float m0 = a0 / p, m1 = a1 / p, m2 = a2 / p;
    mu[((long)b * 3 + 0) * K_ + k] = m0;
    mu[((long)b * 3 + 1) * K_ + k] = m1;
    mu[((long)b * 3 + 2) * K_ + k] = m2;
    yn[b * K_ + k] = m0 * m0 + m1 * m1 + m2 * m2;
  }
}

// ---------------- regularizers ----------------
__global__ __launch_bounds__(256)
void reg_xyz_k(const float* __restrict__ mu, float* __restrict__ out) {
  __shared__ float red[256];
  int b = blockIdx.x, tid = threadIdx.x;
  float acc = 0.f;
  for (int e = tid; e < 4096; e += 256) {
    int m = e >> 6, n2 = e & 63;
    float g = 0.f;
    for (int d = 0; d < 3; ++d)
      g += mu[((long)b * 3 + d) * K_ + m] * mu[((long)b * 3 + d) * K_ + n2];
    acc += fabsf(g - (m == n2 ? 1.f : 0.f));
  }
  float tot = block_reduce_sum256(acc, red);
  if (tid == 0) atomicAdd(out, tot * (1e-7f / 32768.f));
}

__global__ __launch_bounds__(256)
void reg_fea_k(const float* __restrict__ nT, float* __restrict__ out) {
  __shared__ float pm[1024];
  __shared__ float red[256];
  int m = blockIdx.x, b = blockIdx.y, tid = threadIdx.x;
  const float* base = nT + (long)b * K_ * D_;
  *(float4*)&pm[tid * 4] = *(const float4*)(base + (long)m * D_ + tid * 4);
  __syncthreads();
  int n2 = tid >> 2, q = tid & 3;
  const float* pn = base + (long)n2 * D_ + q * 256;
  const float* pml = &pm[q * 256];
  float g = 0.f;
#pragma unroll 8
  for (int d = 0; d < 256; d += 4) {
    float4 v = *(const float4*)(pn + d);
    g += v.x * pml[d] + v.y * pml[d + 1] + v.z * pml[d + 2] + v.w * pml[d + 3];
  }
  g += __shfl_down(g, 2);
  g += __shfl_down(g, 1);
  float acc = (q == 0) ? fabsf(g - (m == n2 ? 1.f : 0.f)) : 0.f;
  float tot = block_reduce_sum256(acc, red);
  if (tid == 0) atomicAdd(out, tot * (1e-4f / 32768.f));
}

// ---------------- mu_fea finalize ----------------
__global__ __launch_bounds__(256)
void mu_finalize(const float* __restrict__ muT_raw, const float* __restrict__ pi_raw,
                 float* __restrict__ n_muT, ushort* __restrict__ nmu_h,
                 ushort* __restrict__ nmu_l) {
  __shared__ float red[256];
  int k = blockIdx.x, b = blockIdx.y, tid = threadIdx.x;
  float p = fmaxf(pi_raw[b * K_ + k], 1e-4f);
  const float* src = muT_raw + ((long)b * K_ + k) * D_;
  float ss = 0.f;
  for (int d = tid; d < D_; d += 256) {
    float v = src[d] / p;
    ss += v * v;
  }
  float tot = block_reduce_sum256(ss, red);
  float inv = 1.f / fmaxf(sqrtf(tot), 1e-12f);
  long o = ((long)b * K_ + k) * D_;
  for (int d = tid; d < D_; d += 256) {
    float v = src[d] / p * inv;
    n_muT[o + d] = v;
    ushort h, l;
    split2(v, h, l);
    nmu_h[o + d] = h;
    nmu_l[o + d] = l;
  }
}

// ---------------- cooperative Sinkhorn v4: flag-based arrival ----------------
__global__ __launch_bounds__(256, 1)
void sinkhorn_coop(const float* __restrict__ cost_f, const float* __restrict__ xyz,
                   const float* __restrict__ mu, const float* __restrict__ yn,
                   const float* __restrict__ logpNK, float* __restrict__ out,
                   unsigned long long* __restrict__ partMS,
                   unsigned int* __restrict__ seq) {
  __shared__ float tile[4][64][68];
  __shared__ float vsh[64];
  __shared__ float wm[4][64];
  __shared__ float wsum[4][64];
  __shared__ float red[256];
  __shared__ float mub[4][64];
  const int tid = threadIdx.x;
  const int g = blockIdx.x & 15;
  const int s = blockIdx.x >> 4;
  const int w = tid >> 6, lane = tid & 63;
  const int i = s * 256 + tid;
  const int b = g & 7;
  const float eps = 1e-3f, ti = 1000.0f;
  const float lgp = -8.317766166719343f;
  const float lgq = -4.1588830833596715f;

  float c[64];
  if (g < 8) {
    if (tid < 64) {
      mub[0][tid] = mu[(b * 3 + 0) * K_ + tid];
      mub[1][tid] = mu[(b * 3 + 1) * K_ + tid];
      mub[2][tid] = mu[(b * 3 + 2) * K_ + tid];
      mub[3][tid] = yn[b * K_ + tid];
      vsh[tid] = 0.f;
    }
    __syncthreads();
    float x0 = xyz[((long)b * 3 + 0) * N_ + i];
    float x1 = xyz[((long)b * 3 + 1) * N_ + i];
    float x2 = xyz[((long)b * 3 + 2) * N_ + i];
    float xn = x0 * x0 + x1 * x1 + x2 * x2;
#pragma unroll
    for (int j = 0; j < 64; ++j)
      c[j] = xn + mub[3][j] - 2.f * (x0 * mub[0][j] + x1 * mub[1][j] + x2 * mub[2][j]);
  } else {
    const float* C = cost_f + (long)b * K_ * N_;
#pragma unroll
    for (int j = 0; j < 64; ++j) c[j] = C[(long)j * N_ + i];
    if (tid < 64) vsh[tid] = 0.f;
    __syncthreads();
  }
  float u = 0.f;

  for (int it = 0; it < 25; ++it) {
    float tj[64];
#pragma unroll
    for (int j = 0; j < 64; ++j) tj[j] = vsh[j] - c[j];
    float dm = -1e30f;
#pragma unroll
    for (int j = 0; j < 64; ++j) dm = fmaxf(dm, tj[j]);
    float ssum = 0.f;
#pragma unroll
    for (int j = 0; j < 64; ++j) ssum += __expf((tj[j] - dm) * ti);
    u = eps * (lgp - ((u + dm) * ti + __logf(ssum))) + u;
#pragma unroll
    for (int j4 = 0; j4 < 16; ++j4) {
      float4 v4;
      v4.x = (u + tj[j4 * 4 + 0]) * ti;
      v4.y = (u + tj[j4 * 4 + 1]) * ti;
      v4.z = (u + tj[j4 * 4 + 2]) * ti;
      v4.w = (u + tj[j4 * 4 + 3]) * ti;
      *(float4*)&tile[w][lane][j4 * 4] = v4;
    }
    __syncthreads();
    float M = -1e30f, S = 0.f;
#pragma unroll
    for (int r = 0; r < 64; ++r) {
      float a = tile[w][r][lane];
      M = fmaxf(M, a);
      S += __expf(a - lgp);
    }
    wm[w][lane] = M;
    wsum[w][lane] = S;
    __syncthreads();
    int buf = it & 1;
    if (tid < 64) {
      float Mb = fmaxf(fmaxf(wm[0][tid], wm[1][tid]), fmaxf(wm[2][tid], wm[3][tid]));
      float Sb = wsum[0][tid] + wsum[1][tid] + wsum[2][tid] + wsum[3][tid];
      unsigned long long pk =
          ((unsigned long long)__float_as_uint(Sb) << 32) | (unsigned long long)__float_as_uint(Mb);
      long idx = (((long)buf * 16 + g) * 16 + s) * 64 + tid;
      __hip_atomic_store(&partMS[idx], pk, __ATOMIC_RELAXED, __HIP_MEMORY_SCOPE_AGENT);
    }
    __syncthreads();
    unsigned target = (unsigned)(it + 1);
    if (tid == 0)
      __hip_atomic_store(&seq[((long)g * 16 + s) * 32], target, __ATOMIC_RELEASE,
                         __HIP_MEMORY_SCOPE_AGENT);
    if (tid < 16) {
      while (__hip_atomic_load(&seq[((long)g * 16 + tid) * 32], __ATOMIC_ACQUIRE,
                               __HIP_MEMORY_SCOPE_AGENT) < target)
        __builtin_amdgcn_s_sleep(1);
    }
    __syncthreads();
    if (tid < 64) {
      long base = (((long)buf * 16 + g) * 16) * 64 + tid;
      float M2 = -1e30f, S2 = 0.f;
#pragma unroll
      for (int p = 0; p < 16; ++p) {
        unsigned long long v =
            __hip_atomic_load(&partMS[base + (long)p * 64], __ATOMIC_RELAXED, __HIP_MEMORY_SCOPE_AGENT);
        M2 = fmaxf(M2, __uint_as_float((unsigned)v));
        S2 += __uint_as_float((unsigned)(v >> 32));
      }
      float lsec = fmaxf(M2, lgp + __logf(S2));
      vsh[tid] = eps * (lgq - lsec) + vsh[tid];
    }
    __syncthreads();
  }

  const float* lp = logpNK + ((long)b * N_ + i) * 64;
  float part = 0.f;
#pragma unroll
  for (int j = 0; j < 64; ++j)
    part += __expf((u + vsh[j] - c[j]) * ti) * lp[j];
  red[tid] = part;
  __syncthreads();
  for (int st2 = 128; st2 > 0; st2 >>= 1) {
    if (tid < st2) red[tid] += red[tid + st2];
    __syncthreads();
  }
  if (tid == 0) atomicAdd(out, -red[0] / (float)B_);
}

// ---------------- launch ----------------
extern "C" void kernel_launch(void* const* d_in, const int* in_sizes, int n_in,
                              void* d_out, int out_size, void* d_ws, size_t ws_size,
                              hipStream_t stream) {
  const float* feature = (const float*)d_in[0];
  const float* xyz = (const float*)d_in[1];
  const float* w1 = (const float*)d_in[2];
  const float* b1 = (const float*)d_in[3];
  const float* g1 = (const float*)d_in[4];
  const float* be1 = (const float*)d_in[5];
  const float* w2 = (const float*)d_in[6];
  const float* b2 = (const float*)d_in[7];
  const float* g2 = (const float*)d_in[8];
  const float* be2 = (const float*)d_in[9];
  const float* w3 = (const float*)d_in[10];
  const float* b3 = (const float*)d_in[11];
  float* out = (float*)d_out;
  float* ws = (float*)d_ws;

  const long RSZ = 16777216L;
  float* regA = ws;
  float* regB1 = ws + RSZ;
  float* sm = ws + 3 * RSZ;

  float* h1raw = regA;
  float* h2raw = regB1;
  const long sz = (long)B_ * N_ * K_;
  float* log_score = regA;
  float* logpNK = regA + sz;
  float* cost_f = regA + 2 * sz;
  ushort* sc_h = (ushort*)(regA + 3 * sz);
  ushort* sc_l = sc_h + sz;

  ushort* Wh1 = (ushort*)sm; sm += 262144;
  ushort* Wl1 = (ushort*)sm; sm += 262144;
  ushort* Wh2 = (ushort*)sm; sm += 131072;
  ushort* Wl2 = (ushort*)sm; sm += 131072;
  ushort* Wh3 = (ushort*)sm; sm += 16384;
  ushort* Wl3 = (ushort*)sm; sm += 16384;
  float* muT_raw = sm; sm += (long)B_ * K_ * D_;
  float* n_muT = sm;   sm += (long)B_ * K_ * D_;
  ushort* nmu_h = (ushort*)sm; sm += 262144;
  ushort* nmu_l = (ushort*)sm; sm += 262144;
  unsigned long long* partMS = (unsigned long long*)sm; sm += 2 * 16 * 16 * 64 * 2;
  unsigned int* seq = (unsigned int*)sm; sm += 16 * 16 * 32;
  float* nrmsq = sm; sm += (long)B_ * N_;
  float* mu_x = sm;   sm += 2048;
  float* yn = sm;     sm += 512;
  float* pi_raw = sm; sm += 512;
  float* rs1 = sm; sm += 512;
  float* rss1 = sm; sm += 512;
  float* rs2 = sm; sm += 512;
  float* rss2 = sm; sm += 512;
  float* sc1 = sm; sm += 512;
  float* sh1 = sm; sm += 512;
  float* sc2 = sm; sm += 512;
  float* sh2 = sm; sm += 512;

  hipMemsetAsync(d_out, 0, sizeof(float) * out_size, stream);
  hipMemsetAsync(pi_raw, 0, 512 * sizeof(float), stream);
  hipMemsetAsync(seq, 0, 16 * 16 * 32 * sizeof(unsigned int), stream);
  hipMemsetAsync(muT_raw, 0, (long)B_ * K_ * D_ * sizeof(float), stream);
  hipMemsetAsync(nrmsq, 0, (long)B_ * N_ * sizeof(float), stream);
  hipMemsetAsync(rs1, 0, 4 * 512 * sizeof(float), stream);

  split_w3<<<3200, 256, 0, stream>>>(w1, w2, w3, Wh1, Wl1, Wh2, Wl2, Wh3, Wl3);
  // conv1
  {
    dim3 g(N_ / 128, H_ / 128, B_);
    conv_bt128<<<g, 256, 0, stream>>>(Wh1, Wl1, feature, nullptr, nullptr, h1raw,
                                      b1, rs1, rss1, nrmsq, D_, (long)D_ * N_,
                                      (long)H_ * N_);
  }
  bn_fin<<<2, 256, 0, stream>>>(rs1, rss1, g1, be1, sc1, sh1);
  // conv2
  {
    dim3 g(N_ / 128, H_ / 128, B_);
    conv_bt128<<<g, 256, 0, stream>>>(Wh2, Wl2, h1raw, sc1, sh1, h2raw, b2, rs2,
                                      rss2, nullptr, H_, (long)H_ * N_,
                                      (long)H_ * N_);
  }
  bn_fin<<<2, 256, 0, stream>>>(rs2, rss2, g2, be2, sc2, sh2);
  // conv3
  {
    dim3 g(N_ / 128, 1, B_);
    conv64_bn<<<g, 256, 0, stream>>>(Wh3, Wl3, h2raw, sc2, sh2, log_score, b3,
                                     H_, (long)H_ * N_, (long)K_ * N_);
  }
  softmax_nk<<<B_ * N_ / 256, 256, 0, stream>>>(log_score, sc_h, sc_l, logpNK,
                                                pi_raw);
  {
    dim3 g(K_, B_);
    mu_xyz_k<<<g, 64, 0, stream>>>(sc_h, sc_l, xyz, pi_raw, mu_x, yn);
  }
  reg_xyz_k<<<B_, 256, 0, stream>>>(mu_x, out);
  // mu_fea
  {
    dim3 g(D_ / 128, 4, B_);
    gemm64_bf<<<g, 256, 0, stream>>>(sc_h, sc_l, feature, muT_raw);
  }
  {
    dim3 g(K_, B_);
    mu_finalize<<<g, 256, 0, stream>>>(muT_raw, pi_raw, n_muT, nmu_h, nmu_l);
  }
  {
    dim3 g(K_, B_);
    reg_fea_k<<<g, 256, 0, stream>>>(n_muT, out);
  }
  // cost_fea
  {
    dim3 g(N_ / 128, 1, B_);
    gemm64_bt<<<g, 256, 0, stream>>>(nmu_h, nmu_l, feature, nrmsq, cost_f);
  }
  // cooperative Sinkhorn + fused loss
  {
    void* kargs[] = {(void*)&cost_f, (void*)&xyz, (void*)&mu_x, (void*)&yn,
                     (void*)&logpNK, (void*)&out, (void*)&partMS, (void*)&seq};
    hipLaunchCooperativeKernel((const void*)sinkhorn_coop, dim3(256), dim3(256),
                               kargs, 0, stream);
  }
}